// Round 11
// baseline (189.278 us; speedup 1.0000x reference)
//
#include <hip/hip_runtime.h>
#include <hip/hip_bf16.h>
#include <math.h>

#define J 50
#define GN 2048          // B*T graphs
#define GK 12800         // J*256
#define GON 512          // pose dim

#define SPLITK 8
#define BKC (GK / SPLITK)   // 1600 K per split
#define NKT (BKC / 64)      // 25 K-steps of 64

typedef short short8 __attribute__((ext_vector_type(8)));
typedef float f32x4 __attribute__((ext_vector_type(4)));

__device__ __forceinline__ float lrelu(float x) { return x > 0.f ? x : 0.2f * x; }
__device__ __forceinline__ ushort f2bu(float f) { __hip_bfloat16 h = __float2bfloat16(f); return *(ushort*)&h; }

// fast GELU: 0.5y(1+tanh(c(y+0.044715y^3))) = y/(1+exp(-2c*u))
__device__ __forceinline__ float gelu_fast(float y) {
    float u = y * (1.f + 0.044715f * y * y);
    float t = __expf(-1.5957691216f * u);
    return y / (1.f + t);
}

// VALU-only 16-lane row sum via DPP row_ror (no LDS pipe, replaces shfl_xor butterfly)
__device__ __forceinline__ float dpp_sum16(float s) {
    int v;
    v = __builtin_amdgcn_update_dpp(0, __builtin_bit_cast(int, s), 0x128, 0xF, 0xF, true);
    s += __builtin_bit_cast(float, v);   // += ror 8
    v = __builtin_amdgcn_update_dpp(0, __builtin_bit_cast(int, s), 0x124, 0xF, 0xF, true);
    s += __builtin_bit_cast(float, v);   // += ror 4
    v = __builtin_amdgcn_update_dpp(0, __builtin_bit_cast(int, s), 0x122, 0xF, 0xF, true);
    s += __builtin_bit_cast(float, v);   // += ror 2
    v = __builtin_amdgcn_update_dpp(0, __builtin_bit_cast(int, s), 0x121, 0xF, 0xF, true);
    s += __builtin_bit_cast(float, v);   // += ror 1
    return s;                            // every lane in row-of-16 has the full sum
}

// ================= fused 3-layer GAT, v3 + DPP reduce + NT output stores =================
// 1 graph/block, 256 threads = 4 waves; wave w owns head w.
// Scores folded into MFMA via Wex = [W@as | W@ad | 0...]; alphas wave-local (no barrier).

template<int DIN, int KPAD, int DOUT, bool LAST>
__device__ __forceinline__ void gat_layer_v3(
    int tid, ushort* xbf, float* esW, float* Acoef, float* statsC, float* statsN,
    const ushort* __restrict__ Wt, const ushort* __restrict__ Rt,
    const ushort* __restrict__ Wex,
    const float* __restrict__ bg, const float* __restrict__ gam,
    const float* __restrict__ bet, ushort* __restrict__ gout)
{
    constexpr int NFW = DOUT / 64;              // n-frags per wave (wave cols == head cols)
    constexpr int GRX = KPAD / 8;               // 16B granules per xbf row
    constexpr int XM  = (GRX < 8 ? GRX : 8) - 1;
    constexpr int NKS = KPAD / 32;              // MFMA K-steps
    const int lane = tid & 63, w = tid >> 6;
    const int lr = lane & 15, lg = lane >> 4;

    f32x4 acc[4][NFW];
    f32x4 ext[4];                               // score frag: col0=es, col1=ed

    // ---------- phase A: h = x @ W  +  es/ed = x @ Wex ----------
    #pragma unroll
    for (int m = 0; m < 4; ++m) {
        ext[m] = (f32x4){0.f, 0.f, 0.f, 0.f};
        #pragma unroll
        for (int nf = 0; nf < NFW; ++nf) acc[m][nf] = (f32x4){0.f, 0.f, 0.f, 0.f};
    }
    #pragma unroll
    for (int ks = 0; ks < NKS; ++ks) {
        short8 af[4];
        #pragma unroll
        for (int m = 0; m < 4; ++m) {
            int row = m * 16 + lr;
            int g = (ks * 4 + lg) ^ (row & XM);
            af[m] = *(const short8*)&xbf[(row * GRX + g) * 8];
        }
        #pragma unroll
        for (int nf = 0; nf < NFW; ++nf) {
            int col = (w * NFW + nf) * 16 + lr;
            short8 bf = *(const short8*)&Wt[col * KPAD + ks * 32 + lg * 8];
            #pragma unroll
            for (int m = 0; m < 4; ++m)
                acc[m][nf] = __builtin_amdgcn_mfma_f32_16x16x32_bf16(af[m], bf, acc[m][nf], 0, 0, 0);
        }
        short8 bfe = *(const short8*)&Wex[(w * 16 + lr) * KPAD + ks * 32 + lg * 8];
        #pragma unroll
        for (int m = 0; m < 4; ++m)
            ext[m] = __builtin_amdgcn_mfma_f32_16x16x32_bf16(af[m], bfe, ext[m], 0, 0, 0);
    }

    // ---------- wave-local es/ed spill (no barrier) ----------
    if (lr < 2) {
        float* dstp = &esW[w * 130 + lr * 65];
        #pragma unroll
        for (int m = 0; m < 4; ++m)
            #pragma unroll
            for (int q = 0; q < 4; ++q)
                dstp[m * 16 + lg * 4 + q] = ext[m][q];
    }
    asm volatile("s_waitcnt lgkmcnt(0)" ::: "memory");

    // ---------- wave-local alphas: one lane per row ----------
    {
        int r = lane;
        const float* ew = &esW[w * 130];
        float es0 = ew[r];
        float esm = ew[r > 0 ? r - 1 : 0];
        float esp = ew[r < 63 ? r + 1 : 63];
        float edj = ew[65 + r];
        float e1 = lrelu(es0 + edj);
        float e0 = (r > 0)     ? lrelu(esm + edj) : -1e30f;
        float e2 = (r < J - 1) ? lrelu(esp + edj) : -1e30f;
        float mx = fmaxf(e1, fmaxf(e0, e2));
        float w0 = __expf(e0 - mx), w1 = __expf(e1 - mx), w2 = __expf(e2 - mx);
        float rden = 1.f / (w0 + w1 + w2);
        Acoef[w * 192 + r]       = w0 * rden;
        Acoef[w * 192 + 64 + r]  = w1 * rden;
        Acoef[w * 192 + 128 + r] = w2 * rden;
    }
    asm volatile("s_waitcnt lgkmcnt(0)" ::: "memory");

    // ---------- in-register 3-point stencil: acc <- alpha-weighted agg ----------
    #pragma unroll
    for (int nf = 0; nf < NFW; ++nf) {
        float tmp[4][4];
        #pragma unroll
        for (int m = 0; m < 4; ++m) {
            int rb = m * 16 + lg * 4;
            float4 c0 = *(const float4*)&Acoef[w * 192 + rb];
            float4 c1 = *(const float4*)&Acoef[w * 192 + 64 + rb];
            float4 c2 = *(const float4*)&Acoef[w * 192 + 128 + rb];
            int mp = m > 0 ? m - 1 : 0, mn = m < 3 ? m + 1 : 3;
            float t1 = __shfl(acc[m][nf][3],  (lane + 48) & 63);
            float t2 = __shfl(acc[mp][nf][3], (lane + 48) & 63);
            float hprev = (lg > 0) ? t1 : t2;
            float b1 = __shfl(acc[m][nf][0],  (lane + 16) & 63);
            float b2 = __shfl(acc[mn][nf][0], (lane + 16) & 63);
            float hnext = (lg < 3) ? b1 : b2;
            tmp[m][0] = c0.x * hprev         + c1.x * acc[m][nf][0] + c2.x * acc[m][nf][1];
            tmp[m][1] = c0.y * acc[m][nf][0] + c1.y * acc[m][nf][1] + c2.y * acc[m][nf][2];
            tmp[m][2] = c0.z * acc[m][nf][1] + c1.z * acc[m][nf][2] + c2.z * acc[m][nf][3];
            tmp[m][3] = c0.w * acc[m][nf][2] + c1.w * acc[m][nf][3] + c2.w * hnext;
        }
        #pragma unroll
        for (int m = 0; m < 4; ++m)
            #pragma unroll
            for (int q = 0; q < 4; ++q) acc[m][nf][q] = tmp[m][q];
    }

    // ---------- phase B: acc += x @ R (MFMA accumulates onto agg), then +bias ----------
    #pragma unroll
    for (int ks = 0; ks < NKS; ++ks) {
        short8 af[4];
        #pragma unroll
        for (int m = 0; m < 4; ++m) {
            int row = m * 16 + lr;
            int g = (ks * 4 + lg) ^ (row & XM);
            af[m] = *(const short8*)&xbf[(row * GRX + g) * 8];
        }
        #pragma unroll
        for (int nf = 0; nf < NFW; ++nf) {
            int col = (w * NFW + nf) * 16 + lr;
            short8 bf = *(const short8*)&Rt[col * KPAD + ks * 32 + lg * 8];
            #pragma unroll
            for (int m = 0; m < 4; ++m)
                acc[m][nf] = __builtin_amdgcn_mfma_f32_16x16x32_bf16(af[m], bf, acc[m][nf], 0, 0, 0);
        }
    }
    #pragma unroll
    for (int nf = 0; nf < NFW; ++nf) {
        float bgv = bg[(w * NFW + nf) * 16 + lr];
        #pragma unroll
        for (int m = 0; m < 4; ++m)
            #pragma unroll
            for (int q = 0; q < 4; ++q) acc[m][nf][q] += bgv;
    }

    // ---------- LN stats: DPP row-sum (VALU-only) + LDS atomic ----------
    #pragma unroll
    for (int m = 0; m < 4; ++m)
        #pragma unroll
        for (int q = 0; q < 4; ++q) {
            float s = 0.f, s2 = 0.f;
            #pragma unroll
            for (int nf = 0; nf < NFW; ++nf) {
                float v = acc[m][nf][q];
                s += v; s2 += v * v;
            }
            s  = dpp_sum16(s);
            s2 = dpp_sum16(s2);
            if (lr == 0) {
                int row = m * 16 + lg * 4 + q;
                atomicAdd(&statsC[row * 2], s);
                atomicAdd(&statsC[row * 2 + 1], s2);
            }
        }
    __syncthreads();   // B3
    if (tid < 64) {
        float S = statsC[tid * 2], S2 = statsC[tid * 2 + 1];
        float mu = S * (1.f / DOUT);
        float var = S2 * (1.f / DOUT) - mu * mu;
        statsC[tid * 2] = mu;
        statsC[tid * 2 + 1] = rsqrtf(var + 1e-5f);
    }
    __syncthreads();   // B4

    // ---------- apply LN + GELU, write next-layer input; zero next stats ----------
    constexpr int NGR = DOUT / 8;
    constexpr int NXM = (NGR < 8 ? NGR : 8) - 1;
    #pragma unroll
    for (int nf = 0; nf < NFW; ++nf) {
        int col = (w * NFW + nf) * 16 + lr;
        float ga = gam[col], be = bet[col];
        #pragma unroll
        for (int m = 0; m < 4; ++m)
            #pragma unroll
            for (int q = 0; q < 4; ++q) {
                int row = m * 16 + lg * 4 + q;
                float mu = statsC[row * 2], inv = statsC[row * 2 + 1];
                float y = (acc[m][nf][q] - mu) * inv * ga + be;
                float ge = gelu_fast(y);
                if (LAST) {
                    if (row < J)
                        __builtin_nontemporal_store(f2bu(ge), &gout[row * 256 + col]);
                } else {
                    xbf[(row * NGR + ((col >> 3) ^ (row & NXM))) * 8 + (col & 7)] =
                        (row < J) ? f2bu(ge) : (ushort)0;
                }
            }
    }
    if (tid < 128) statsN[tid] = 0.f;
    __syncthreads();   // B5
}

__global__ __launch_bounds__(256, 4) void gat_mfma(
    const float* __restrict__ pose,
    const ushort* __restrict__ Wt0, const ushort* __restrict__ Rt0,
    const ushort* __restrict__ Wt1, const ushort* __restrict__ Rt1,
    const ushort* __restrict__ Wt2, const ushort* __restrict__ Rt2,
    const ushort* __restrict__ wex0, const ushort* __restrict__ wex1,
    const ushort* __restrict__ wex2,
    const float* bg0, const float* g0v, const float* b0v,
    const float* bg1, const float* g1v, const float* b1v,
    const float* bg2, const float* g2v, const float* b2v,
    ushort* __restrict__ xg)
{
    __shared__ ushort xbf[64 * 128];   // 16 KB (max KPAD=128)
    __shared__ float esW[4 * 130];     // per-wave es|ed slabs
    __shared__ float Acoef[4 * 192];   // per-wave a0|a1|a2
    __shared__ float sA[128], sB[128]; // double-buffered LN partials
    int g = blockIdx.x, tid = threadIdx.x;

    // load pose -> xbf[64][32] bf16, swizzled (GRX=4, mask 3), zero-padded
    for (int i = tid; i < 64 * 32; i += 256) {
        int row = i >> 5, c = i & 31;
        float v = (row < J && c < 3)
            ? __builtin_nontemporal_load(&pose[(size_t)g * (J * 3) + row * 3 + c]) : 0.f;
        xbf[(row * 4 + ((c >> 3) ^ (row & 3))) * 8 + (c & 7)] = f2bu(v);
    }
    if (tid < 128) sA[tid] = 0.f;
    __syncthreads();
    gat_layer_v3<3,   32,  64, false>(tid, xbf, esW, Acoef, sA, sB, Wt0, Rt0, wex0,
                                      bg0, g0v, b0v, nullptr);
    gat_layer_v3<64,  64, 128, false>(tid, xbf, esW, Acoef, sB, sA, Wt1, Rt1, wex1,
                                      bg1, g1v, b1v, nullptr);
    gat_layer_v3<128,128, 256, true >(tid, xbf, esW, Acoef, sA, sB, Wt2, Rt2, wex2,
                                      bg2, g2v, b2v, xg + (size_t)g * GK);
}

// ================= fused prep: weights + wex + fpW transpose in one launch =================
// blocks [0,336): transposed bf16 weights; [336,392): Wex fold; [392,1992): fpW -> Bt
__global__ __launch_bounds__(256) void prep_all(
    const float* __restrict__ W0, const float* __restrict__ R0,
    const float* __restrict__ W1, const float* __restrict__ R1,
    const float* __restrict__ W2, const float* __restrict__ R2,
    const float* __restrict__ as0, const float* __restrict__ ad0,
    const float* __restrict__ as1, const float* __restrict__ ad1,
    const float* __restrict__ as2, const float* __restrict__ ad2,
    const float* __restrict__ fpW,
    ushort* __restrict__ wt, ushort* __restrict__ wex, ushort* __restrict__ Bt)
{
    __shared__ float tile[64][65];
    int bid = blockIdx.x, tid = threadIdx.x;
    if (bid < 336) {
        int i = bid * 256 + tid;
        if (i < 2048)       { int n = i >> 5, k = i & 31;                    wt[i] = f2bu(k < 3 ? W0[k * 64 + n] : 0.f); }
        else if (i < 4096)  { int j = i - 2048;  int n = j >> 5, k = j & 31; wt[i] = f2bu(k < 3 ? R0[k * 64 + n] : 0.f); }
        else if (i < 12288) { int j = i - 4096;  int n = j >> 6, k = j & 63; wt[i] = f2bu(W1[k * 128 + n]); }
        else if (i < 20480) { int j = i - 12288; int n = j >> 6, k = j & 63; wt[i] = f2bu(R1[k * 128 + n]); }
        else if (i < 53248) { int j = i - 20480; int n = j >> 7, k = j & 127; wt[i] = f2bu(W2[k * 256 + n]); }
        else if (i < 86016) { int j = i - 53248; int n = j >> 7, k = j & 127; wt[i] = f2bu(R2[k * 256 + n]); }
    } else if (bid < 392) {
        int i = (bid - 336) * 256 + tid;
        const float *as_, *ad_, *W; ushort* dst; int KPAD, DIN, DOUT, idx;
        if (i < 2048)       { idx = i;         KPAD = 32;  DIN = 3;   DOUT = 64;  as_ = as0; ad_ = ad0; W = W0; dst = wex; }
        else if (i < 6144)  { idx = i - 2048;  KPAD = 64;  DIN = 64;  DOUT = 128; as_ = as1; ad_ = ad1; W = W1; dst = wex + 2048; }
        else if (i < 14336) { idx = i - 6144;  KPAD = 128; DIN = 128; DOUT = 256; as_ = as2; ad_ = ad2; W = W2; dst = wex + 6144; }
        else return;
        int k = idx % KPAD;
        int col = (idx / KPAD) & 15;
        int h = idx / (KPAD * 16);
        int C = DOUT / 4;
        float v = 0.f;
        if (col < 2 && k < DIN) {
            const float* a = (col == 0) ? as_ : ad_;
            for (int c = 0; c < C; ++c) v += W[k * DOUT + h * C + c] * a[h * C + c];
        }
        dst[idx] = f2bu(v);
    } else {
        int b = bid - 392;
        int kb = (b >> 3) * 64;
        int nb = (b & 7) * 64;
        #pragma unroll
        for (int i = 0; i < 16; ++i) {
            int idx = tid + i * 256;
            int r = idx >> 6, c = idx & 63;
            tile[r][c] = fpW[(size_t)(kb + r) * GON + nb + c];
        }
        __syncthreads();
        #pragma unroll
        for (int i = 0; i < 16; ++i) {
            int idx = tid + i * 256;
            int nr = idx >> 6, kc = idx & 63;
            Bt[(size_t)(nb + nr) * GK + kb + kc] = f2bu(tile[kc][nr]);
        }
    }
}

// ---------------- MFMA GEMM (verified R2-R10; NT parts store) ----------------
__global__ __launch_bounds__(512) void final_gemm_mfma(
    const ushort* __restrict__ A,   // [2048][12800] bf16
    const ushort* __restrict__ Bt,  // [512][12800] bf16
    float* __restrict__ parts)      // [SPLITK][2048][512] f32
{
    __shared__ ushort Asm[2][128 * 64];
    __shared__ ushort Bsm[2][128 * 64];
    int tid = threadIdx.x;
    int bid = blockIdx.x;
    int tileid = bid & 63, sp = bid >> 6;
    int rt = tileid >> 2, ct = tileid & 3;
    int ar0 = rt * 128, bc0 = ct * 128;
    int kbase = sp * BKC;

    int lane = tid & 63, wid = tid >> 6;
    int wm = wid >> 2, wn = wid & 3;

    f32x4 acc[4][2];
    #pragma unroll
    for (int mi = 0; mi < 4; ++mi)
        #pragma unroll
        for (int ni = 0; ni < 2; ++ni)
            acc[mi][ni] = (f32x4){0.f, 0.f, 0.f, 0.f};

#define STAGE(pg, k0)                                                              \
    do {                                                                           \
        _Pragma("unroll")                                                          \
        for (int s_ = 0; s_ < 4; ++s_) {                                           \
            int g_ = tid + s_ * 512;                                               \
            int gg_ = g_ & 1023;                                                   \
            int row_ = gg_ >> 3, cg_ = gg_ & 7;                                    \
            int csw_ = cg_ ^ (row_ & 7);                                           \
            const ushort* src_;                                                    \
            ushort* dst_;                                                          \
            if (g_ < 1024) {                                                       \
                src_ = A + (size_t)(ar0 + row_) * GK + (k0) + csw_ * 8;            \
                dst_ = &Asm[pg][gg_ * 8];                                          \
            } else {                                                               \
                src_ = Bt + (size_t)(bc0 + row_) * GK + (k0) + csw_ * 8;           \
                dst_ = &Bsm[pg][gg_ * 8];                                          \
            }                                                                      \
            __builtin_amdgcn_global_load_lds(                                      \
                (const __attribute__((address_space(1))) void*)src_,               \
                (__attribute__((address_space(3))) void*)dst_, 16, 0, 0);          \
        }                                                                          \
    } while (0)

    STAGE(0, kbase);
    __syncthreads();
    int pg = 0;
    for (int kt = 0; kt < NKT; ++kt) {
        if (kt + 1 < NKT) STAGE(pg ^ 1, kbase + (kt + 1) * 64);
        const ushort* Ab = Asm[pg];
        const ushort* Bb = Bsm[pg];
        short8 afr[4][2], bfr[2][2];
        #pragma unroll
        for (int mi = 0; mi < 4; ++mi)
            #pragma unroll
            for (int ks = 0; ks < 2; ++ks) {
                int row = wm * 64 + mi * 16 + (lane & 15);
                int gs = (ks * 4 + (lane >> 4)) ^ (row & 7);
                afr[mi][ks] = *(const short8*)&Ab[row * 64 + gs * 8];
            }
        #pragma unroll
        for (int ni = 0; ni < 2; ++ni)
            #pragma unroll
            for (int ks = 0; ks < 2; ++ks) {
                int row = wn * 32 + ni * 16 + (lane & 15);
                int gs = (ks * 4 + (lane >> 4)) ^ (row & 7);
                bfr[ni][ks] = *(const short8*)&Bb[row * 64 + gs * 8];
            }
        #pragma unroll
        for (int ks = 0; ks < 2; ++ks)
            #pragma unroll
            for (int mi = 0; mi < 4; ++mi)
                #pragma unroll
                for (int ni = 0; ni < 2; ++ni)
                    acc[mi][ni] = __builtin_amdgcn_mfma_f32_16x16x32_bf16(
                        afr[mi][ks], bfr[ni][ks], acc[mi][ni], 0, 0, 0);
        __syncthreads();
        pg ^= 1;
    }
#undef STAGE

    float* outp = parts + (size_t)sp * GN * GON;
    #pragma unroll
    for (int mi = 0; mi < 4; ++mi)
        #pragma unroll
        for (int ni = 0; ni < 2; ++ni)
            #pragma unroll
            for (int r = 0; r < 4; ++r) {
                int row = ar0 + wm * 64 + mi * 16 + (lane >> 4) * 4 + r;
                int col = bc0 + wn * 32 + ni * 16 + (lane & 15);
                __builtin_nontemporal_store(acc[mi][ni][r], &outp[(size_t)row * GON + col]);
            }
}

// ---------------- reduce partials + fpb + LayerNorm -> d_out ----------------
__global__ __launch_bounds__(256) void final_reduce_ln(
    const float* __restrict__ parts, float* __restrict__ out,
    const float* __restrict__ fpb, const float* __restrict__ fng,
    const float* __restrict__ fnb)
{
    int row = blockIdx.x * 4 + (threadIdx.x >> 6);
    int lane = threadIdx.x & 63;
    float v[8];
    float sum = 0.f;
    #pragma unroll
    for (int cc = 0; cc < 8; ++cc) {
        int o = lane + (cc << 6);
        float a = 0.f;
        #pragma unroll
        for (int s = 0; s < SPLITK; ++s)
            a += __builtin_nontemporal_load(&parts[(size_t)s * GN * GON + (size_t)row * GON + o]);
        v[cc] = a + fpb[o];
        sum += v[cc];
    }
    #pragma unroll
    for (int off = 32; off >= 1; off >>= 1) sum += __shfl_xor(sum, off, 64);
    float mu = sum * (1.f / GON);
    float sq = 0.f;
    #pragma unroll
    for (int cc = 0; cc < 8; ++cc) { float d = v[cc] - mu; sq += d * d; }
    #pragma unroll
    for (int off = 32; off >= 1; off >>= 1) sq += __shfl_xor(sq, off, 64);
    float inv = rsqrtf(sq * (1.f / GON) + 1e-5f);
    #pragma unroll
    for (int cc = 0; cc < 8; ++cc) {
        int o = lane + (cc << 6);
        __builtin_nontemporal_store((v[cc] - mu) * inv * fng[o] + fnb[o],
                                    &out[(size_t)row * GON + o]);
    }
}

extern "C" void kernel_launch(void* const* d_in, const int* in_sizes, int n_in,
                              void* d_out, int out_size, void* d_ws, size_t ws_size,
                              hipStream_t stream) {
    (void)in_sizes; (void)n_in; (void)out_size; (void)ws_size;
    const float* pose = (const float*)d_in[0];
    const float *W0 = (const float*)d_in[1],  *as0 = (const float*)d_in[2],
                *ad0 = (const float*)d_in[3], *bg0 = (const float*)d_in[4],
                *R0 = (const float*)d_in[5],  *g0v = (const float*)d_in[6],
                *b0v = (const float*)d_in[7];
    const float *W1 = (const float*)d_in[8],  *as1 = (const float*)d_in[9],
                *ad1 = (const float*)d_in[10],*bg1 = (const float*)d_in[11],
                *R1 = (const float*)d_in[12], *g1v = (const float*)d_in[13],
                *b1v = (const float*)d_in[14];
    const float *W2 = (const float*)d_in[15], *as2 = (const float*)d_in[16],
                *ad2 = (const float*)d_in[17],*bg2 = (const float*)d_in[18],
                *R2 = (const float*)d_in[19], *g2v = (const float*)d_in[20],
                *b2v = (const float*)d_in[21];
    const float* fpW = (const float*)d_in[22];
    const float* fpb = (const float*)d_in[23];
    const float* fng = (const float*)d_in[24];
    const float* fnb = (const float*)d_in[25];

    // workspace: xg | Bt | parts | wt (86016) | wex (14336)
    ushort* xg = (ushort*)d_ws;                               // 52,428,800 B
    ushort* Bt = xg + (size_t)GN * GK;                        // +13,107,200 B
    float* parts = (float*)(Bt + (size_t)GON * GK);           // +33,554,432 B
    ushort* wsm = (ushort*)(parts + (size_t)SPLITK * GN * GON); // +172,032 B
    ushort *Wt0 = wsm,          *Rt0 = wsm + 2048;
    ushort *Wt1 = wsm + 4096,   *Rt1 = wsm + 12288;
    ushort *Wt2 = wsm + 20480,  *Rt2 = wsm + 53248;
    ushort* wex = wsm + 86016;                                // +28,672 B (~99.29 MB total)
    ushort *wex0 = wex, *wex1 = wex + 2048, *wex2 = wex + 6144;
    float* out = (float*)d_out;

    prep_all<<<392 + (GK / 64) * (GON / 64), 256, 0, stream>>>(
        W0, R0, W1, R1, W2, R2,
        as0, ad0, as1, ad1, as2, ad2,
        fpW, wsm, wex, Bt);
    gat_mfma<<<GN, 256, 0, stream>>>(pose,
        Wt0, Rt0, Wt1, Rt1, Wt2, Rt2,
        wex0, wex1, wex2,
        bg0, g0v, b0v,
        bg1, g1v, b1v,
        bg2, g2v, b2v, xg);
    final_gemm_mfma<<<64 * SPLITK, 512, 0, stream>>>(xg, Bt, parts);
    final_reduce_ln<<<GN / 4, 256, 0, stream>>>(parts, out, fpb, fng, fnb);
}

// Round 12
// 172.339 us; speedup vs baseline: 1.0983x; 1.0983x over previous
//
#include <hip/hip_runtime.h>
#include <hip/hip_bf16.h>
#include <math.h>

#define J 50
#define GN 2048          // B*T graphs
#define GK 12800         // J*256
#define GON 512          // pose dim

#define SPLITK 8
#define BKC (GK / SPLITK)   // 1600 K per split
#define NKT (BKC / 64)      // 25 K-steps of 64

typedef short short8 __attribute__((ext_vector_type(8)));
typedef float f32x4 __attribute__((ext_vector_type(4)));

__device__ __forceinline__ float lrelu(float x) { return x > 0.f ? x : 0.2f * x; }
__device__ __forceinline__ ushort f2bu(float f) { __hip_bfloat16 h = __float2bfloat16(f); return *(ushort*)&h; }

// fast GELU: 0.5y(1+tanh(c(y+0.044715y^3))) = y/(1+exp(-2c*u))
__device__ __forceinline__ float gelu_fast(float y) {
    float u = y * (1.f + 0.044715f * y * y);
    float t = __expf(-1.5957691216f * u);
    return y / (1.f + t);
}

// VALU-only 16-lane row sum via DPP row_ror (no LDS pipe)
__device__ __forceinline__ float dpp_sum16(float s) {
    int v;
    v = __builtin_amdgcn_update_dpp(0, __builtin_bit_cast(int, s), 0x128, 0xF, 0xF, true);
    s += __builtin_bit_cast(float, v);   // += ror 8
    v = __builtin_amdgcn_update_dpp(0, __builtin_bit_cast(int, s), 0x124, 0xF, 0xF, true);
    s += __builtin_bit_cast(float, v);   // += ror 4
    v = __builtin_amdgcn_update_dpp(0, __builtin_bit_cast(int, s), 0x122, 0xF, 0xF, true);
    s += __builtin_bit_cast(float, v);   // += ror 2
    v = __builtin_amdgcn_update_dpp(0, __builtin_bit_cast(int, s), 0x121, 0xF, 0xF, true);
    s += __builtin_bit_cast(float, v);   // += ror 1
    return s;
}

// ================= fused 3-layer GAT (R10 structure, LN-apply restructured) =================
// 1 graph/block, 256 threads = 4 waves; wave w owns head w.
// Scores folded into MFMA via Wex = [W@as | W@ad | 0...]; alphas wave-local (no barrier).

template<int DIN, int KPAD, int DOUT, bool LAST>
__device__ __forceinline__ void gat_layer_v3(
    int tid, ushort* xbf, float* esW, float* Acoef, float* statsC, float* statsN,
    const ushort* __restrict__ Wt, const ushort* __restrict__ Rt,
    const ushort* __restrict__ Wex,
    const float* __restrict__ bg, const float* __restrict__ gam,
    const float* __restrict__ bet, ushort* __restrict__ gout)
{
    constexpr int NFW = DOUT / 64;              // n-frags per wave (wave cols == head cols)
    constexpr int GRX = KPAD / 8;               // 16B granules per xbf row
    constexpr int XM  = (GRX < 8 ? GRX : 8) - 1;
    constexpr int NKS = KPAD / 32;              // MFMA K-steps
    const int lane = tid & 63, w = tid >> 6;
    const int lr = lane & 15, lg = lane >> 4;

    f32x4 acc[4][NFW];
    f32x4 ext[4];                               // score frag: col0=es, col1=ed

    // ---------- phase A: h = x @ W  +  es/ed = x @ Wex ----------
    #pragma unroll
    for (int m = 0; m < 4; ++m) {
        ext[m] = (f32x4){0.f, 0.f, 0.f, 0.f};
        #pragma unroll
        for (int nf = 0; nf < NFW; ++nf) acc[m][nf] = (f32x4){0.f, 0.f, 0.f, 0.f};
    }
    #pragma unroll
    for (int ks = 0; ks < NKS; ++ks) {
        short8 af[4];
        #pragma unroll
        for (int m = 0; m < 4; ++m) {
            int row = m * 16 + lr;
            int g = (ks * 4 + lg) ^ (row & XM);
            af[m] = *(const short8*)&xbf[(row * GRX + g) * 8];
        }
        #pragma unroll
        for (int nf = 0; nf < NFW; ++nf) {
            int col = (w * NFW + nf) * 16 + lr;
            short8 bf = *(const short8*)&Wt[col * KPAD + ks * 32 + lg * 8];
            #pragma unroll
            for (int m = 0; m < 4; ++m)
                acc[m][nf] = __builtin_amdgcn_mfma_f32_16x16x32_bf16(af[m], bf, acc[m][nf], 0, 0, 0);
        }
        short8 bfe = *(const short8*)&Wex[(w * 16 + lr) * KPAD + ks * 32 + lg * 8];
        #pragma unroll
        for (int m = 0; m < 4; ++m)
            ext[m] = __builtin_amdgcn_mfma_f32_16x16x32_bf16(af[m], bfe, ext[m], 0, 0, 0);
    }

    // ---------- wave-local es/ed spill (no barrier) ----------
    if (lr < 2) {
        float* dstp = &esW[w * 130 + lr * 65];
        #pragma unroll
        for (int m = 0; m < 4; ++m)
            #pragma unroll
            for (int q = 0; q < 4; ++q)
                dstp[m * 16 + lg * 4 + q] = ext[m][q];
    }
    asm volatile("s_waitcnt lgkmcnt(0)" ::: "memory");

    // ---------- wave-local alphas: one lane per row ----------
    {
        int r = lane;
        const float* ew = &esW[w * 130];
        float es0 = ew[r];
        float esm = ew[r > 0 ? r - 1 : 0];
        float esp = ew[r < 63 ? r + 1 : 63];
        float edj = ew[65 + r];
        float e1 = lrelu(es0 + edj);
        float e0 = (r > 0)     ? lrelu(esm + edj) : -1e30f;
        float e2 = (r < J - 1) ? lrelu(esp + edj) : -1e30f;
        float mx = fmaxf(e1, fmaxf(e0, e2));
        float w0 = __expf(e0 - mx), w1 = __expf(e1 - mx), w2 = __expf(e2 - mx);
        float rden = 1.f / (w0 + w1 + w2);
        Acoef[w * 192 + r]       = w0 * rden;
        Acoef[w * 192 + 64 + r]  = w1 * rden;
        Acoef[w * 192 + 128 + r] = w2 * rden;
    }
    asm volatile("s_waitcnt lgkmcnt(0)" ::: "memory");

    // ---------- in-register 3-point stencil: acc <- alpha-weighted agg ----------
    #pragma unroll
    for (int nf = 0; nf < NFW; ++nf) {
        float tmp[4][4];
        #pragma unroll
        for (int m = 0; m < 4; ++m) {
            int rb = m * 16 + lg * 4;
            float4 c0 = *(const float4*)&Acoef[w * 192 + rb];
            float4 c1 = *(const float4*)&Acoef[w * 192 + 64 + rb];
            float4 c2 = *(const float4*)&Acoef[w * 192 + 128 + rb];
            int mp = m > 0 ? m - 1 : 0, mn = m < 3 ? m + 1 : 3;
            float t1 = __shfl(acc[m][nf][3],  (lane + 48) & 63);
            float t2 = __shfl(acc[mp][nf][3], (lane + 48) & 63);
            float hprev = (lg > 0) ? t1 : t2;
            float b1 = __shfl(acc[m][nf][0],  (lane + 16) & 63);
            float b2 = __shfl(acc[mn][nf][0], (lane + 16) & 63);
            float hnext = (lg < 3) ? b1 : b2;
            tmp[m][0] = c0.x * hprev         + c1.x * acc[m][nf][0] + c2.x * acc[m][nf][1];
            tmp[m][1] = c0.y * acc[m][nf][0] + c1.y * acc[m][nf][1] + c2.y * acc[m][nf][2];
            tmp[m][2] = c0.z * acc[m][nf][1] + c1.z * acc[m][nf][2] + c2.z * acc[m][nf][3];
            tmp[m][3] = c0.w * acc[m][nf][2] + c1.w * acc[m][nf][3] + c2.w * hnext;
        }
        #pragma unroll
        for (int m = 0; m < 4; ++m)
            #pragma unroll
            for (int q = 0; q < 4; ++q) acc[m][nf][q] = tmp[m][q];
    }

    // ---------- phase B: acc += x @ R (MFMA accumulates onto agg), then +bias ----------
    #pragma unroll
    for (int ks = 0; ks < NKS; ++ks) {
        short8 af[4];
        #pragma unroll
        for (int m = 0; m < 4; ++m) {
            int row = m * 16 + lr;
            int g = (ks * 4 + lg) ^ (row & XM);
            af[m] = *(const short8*)&xbf[(row * GRX + g) * 8];
        }
        #pragma unroll
        for (int nf = 0; nf < NFW; ++nf) {
            int col = (w * NFW + nf) * 16 + lr;
            short8 bf = *(const short8*)&Rt[col * KPAD + ks * 32 + lg * 8];
            #pragma unroll
            for (int m = 0; m < 4; ++m)
                acc[m][nf] = __builtin_amdgcn_mfma_f32_16x16x32_bf16(af[m], bf, acc[m][nf], 0, 0, 0);
        }
    }
    #pragma unroll
    for (int nf = 0; nf < NFW; ++nf) {
        float bgv = bg[(w * NFW + nf) * 16 + lr];
        #pragma unroll
        for (int m = 0; m < 4; ++m)
            #pragma unroll
            for (int q = 0; q < 4; ++q) acc[m][nf][q] += bgv;
    }

    // ---------- LN stats: DPP row-sum (VALU-only) + LDS atomic ----------
    #pragma unroll
    for (int m = 0; m < 4; ++m)
        #pragma unroll
        for (int q = 0; q < 4; ++q) {
            float s = 0.f, s2 = 0.f;
            #pragma unroll
            for (int nf = 0; nf < NFW; ++nf) {
                float v = acc[m][nf][q];
                s += v; s2 += v * v;
            }
            s  = dpp_sum16(s);
            s2 = dpp_sum16(s2);
            if (lr == 0) {
                int row = m * 16 + lg * 4 + q;
                atomicAdd(&statsC[row * 2], s);
                atomicAdd(&statsC[row * 2 + 1], s2);
            }
        }
    __syncthreads();   // B3
    if (tid < 64) {
        float S = statsC[tid * 2], S2 = statsC[tid * 2 + 1];
        float mu = S * (1.f / DOUT);
        float var = S2 * (1.f / DOUT) - mu * mu;
        statsC[tid * 2] = mu;
        statsC[tid * 2 + 1] = rsqrtf(var + 1e-5f);
    }
    __syncthreads();   // B4

    // ---------- apply LN + GELU (row-outer: stats read once/row, 2-fma form) ----------
    constexpr int NGR = DOUT / 8;
    constexpr int NXM = (NGR < 8 ? NGR : 8) - 1;
    {
        float gav[NFW], bev[NFW];
        #pragma unroll
        for (int nf = 0; nf < NFW; ++nf) {
            int col = (w * NFW + nf) * 16 + lr;
            gav[nf] = gam[col]; bev[nf] = bet[col];
        }
        #pragma unroll
        for (int m = 0; m < 4; ++m)
            #pragma unroll
            for (int q = 0; q < 4; ++q) {
                int row = m * 16 + lg * 4 + q;
                float mu = statsC[row * 2], inv = statsC[row * 2 + 1];
                float miv = -mu * inv;
                #pragma unroll
                for (int nf = 0; nf < NFW; ++nf) {
                    int col = (w * NFW + nf) * 16 + lr;
                    float y = fmaf(acc[m][nf][q], inv, miv);
                    y = fmaf(y, gav[nf], bev[nf]);
                    float ge = gelu_fast(y);
                    if (LAST) {
                        if (row < J) gout[row * 256 + col] = f2bu(ge);
                    } else {
                        xbf[(row * NGR + ((col >> 3) ^ (row & NXM))) * 8 + (col & 7)] =
                            (row < J) ? f2bu(ge) : (ushort)0;
                    }
                }
            }
    }
    if (tid < 128) statsN[tid] = 0.f;
    __syncthreads();   // B5
}

__global__ __launch_bounds__(256, 4) void gat_mfma(
    const float* __restrict__ pose,
    const ushort* __restrict__ Wt0, const ushort* __restrict__ Rt0,
    const ushort* __restrict__ Wt1, const ushort* __restrict__ Rt1,
    const ushort* __restrict__ Wt2, const ushort* __restrict__ Rt2,
    const ushort* __restrict__ wex0, const ushort* __restrict__ wex1,
    const ushort* __restrict__ wex2,
    const float* bg0, const float* g0v, const float* b0v,
    const float* bg1, const float* g1v, const float* b1v,
    const float* bg2, const float* g2v, const float* b2v,
    ushort* __restrict__ xg)
{
    __shared__ ushort xbf[64 * 128];   // 16 KB (max KPAD=128)
    __shared__ float esW[4 * 130];     // per-wave es|ed slabs
    __shared__ float Acoef[4 * 192];   // per-wave a0|a1|a2
    __shared__ float sA[128], sB[128]; // double-buffered LN partials
    int g = blockIdx.x, tid = threadIdx.x;

    // load pose -> xbf[64][32] bf16, swizzled (GRX=4, mask 3), zero-padded
    for (int i = tid; i < 64 * 32; i += 256) {
        int row = i >> 5, c = i & 31;
        float v = (row < J && c < 3) ? pose[(size_t)g * (J * 3) + row * 3 + c] : 0.f;
        xbf[(row * 4 + ((c >> 3) ^ (row & 3))) * 8 + (c & 7)] = f2bu(v);
    }
    if (tid < 128) sA[tid] = 0.f;
    __syncthreads();
    gat_layer_v3<3,   32,  64, false>(tid, xbf, esW, Acoef, sA, sB, Wt0, Rt0, wex0,
                                      bg0, g0v, b0v, nullptr);
    gat_layer_v3<64,  64, 128, false>(tid, xbf, esW, Acoef, sB, sA, Wt1, Rt1, wex1,
                                      bg1, g1v, b1v, nullptr);
    gat_layer_v3<128,128, 256, true >(tid, xbf, esW, Acoef, sA, sB, Wt2, Rt2, wex2,
                                      bg2, g2v, b2v, xg + (size_t)g * GK);
}

// ================= fused prep: weights + wex + fpW transpose in one launch =================
// blocks [0,336): transposed bf16 weights; [336,392): Wex fold; [392,1992): fpW -> Bt
__global__ __launch_bounds__(256) void prep_all(
    const float* __restrict__ W0, const float* __restrict__ R0,
    const float* __restrict__ W1, const float* __restrict__ R1,
    const float* __restrict__ W2, const float* __restrict__ R2,
    const float* __restrict__ as0, const float* __restrict__ ad0,
    const float* __restrict__ as1, const float* __restrict__ ad1,
    const float* __restrict__ as2, const float* __restrict__ ad2,
    const float* __restrict__ fpW,
    ushort* __restrict__ wt, ushort* __restrict__ wex, ushort* __restrict__ Bt)
{
    __shared__ float tile[64][65];
    int bid = blockIdx.x, tid = threadIdx.x;
    if (bid < 336) {
        int i = bid * 256 + tid;
        if (i < 2048)       { int n = i >> 5, k = i & 31;                    wt[i] = f2bu(k < 3 ? W0[k * 64 + n] : 0.f); }
        else if (i < 4096)  { int j = i - 2048;  int n = j >> 5, k = j & 31; wt[i] = f2bu(k < 3 ? R0[k * 64 + n] : 0.f); }
        else if (i < 12288) { int j = i - 4096;  int n = j >> 6, k = j & 63; wt[i] = f2bu(W1[k * 128 + n]); }
        else if (i < 20480) { int j = i - 12288; int n = j >> 6, k = j & 63; wt[i] = f2bu(R1[k * 128 + n]); }
        else if (i < 53248) { int j = i - 20480; int n = j >> 7, k = j & 127; wt[i] = f2bu(W2[k * 256 + n]); }
        else if (i < 86016) { int j = i - 53248; int n = j >> 7, k = j & 127; wt[i] = f2bu(R2[k * 256 + n]); }
    } else if (bid < 392) {
        int i = (bid - 336) * 256 + tid;
        const float *as_, *ad_, *W; ushort* dst; int KPAD, DIN, DOUT, idx;
        if (i < 2048)       { idx = i;         KPAD = 32;  DIN = 3;   DOUT = 64;  as_ = as0; ad_ = ad0; W = W0; dst = wex; }
        else if (i < 6144)  { idx = i - 2048;  KPAD = 64;  DIN = 64;  DOUT = 128; as_ = as1; ad_ = ad1; W = W1; dst = wex + 2048; }
        else if (i < 14336) { idx = i - 6144;  KPAD = 128; DIN = 128; DOUT = 256; as_ = as2; ad_ = ad2; W = W2; dst = wex + 6144; }
        else return;
        int k = idx % KPAD;
        int col = (idx / KPAD) & 15;
        int h = idx / (KPAD * 16);
        int C = DOUT / 4;
        float v = 0.f;
        if (col < 2 && k < DIN) {
            const float* a = (col == 0) ? as_ : ad_;
            for (int c = 0; c < C; ++c) v += W[k * DOUT + h * C + c] * a[h * C + c];
        }
        dst[idx] = f2bu(v);
    } else {
        int b = bid - 392;
        int kb = (b >> 3) * 64;
        int nb = (b & 7) * 64;
        #pragma unroll
        for (int i = 0; i < 16; ++i) {
            int idx = tid + i * 256;
            int r = idx >> 6, c = idx & 63;
            tile[r][c] = fpW[(size_t)(kb + r) * GON + nb + c];
        }
        __syncthreads();
        #pragma unroll
        for (int i = 0; i < 16; ++i) {
            int idx = tid + i * 256;
            int nr = idx >> 6, kc = idx & 63;
            Bt[(size_t)(nb + nr) * GK + kb + kc] = f2bu(tile[kc][nr]);
        }
    }
}

// ---------------- MFMA GEMM (unchanged, verified R2-R10) ----------------
__global__ __launch_bounds__(512) void final_gemm_mfma(
    const ushort* __restrict__ A,   // [2048][12800] bf16
    const ushort* __restrict__ Bt,  // [512][12800] bf16
    float* __restrict__ parts)      // [SPLITK][2048][512] f32
{
    __shared__ ushort Asm[2][128 * 64];
    __shared__ ushort Bsm[2][128 * 64];
    int tid = threadIdx.x;
    int bid = blockIdx.x;
    int tileid = bid & 63, sp = bid >> 6;
    int rt = tileid >> 2, ct = tileid & 3;
    int ar0 = rt * 128, bc0 = ct * 128;
    int kbase = sp * BKC;

    int lane = tid & 63, wid = tid >> 6;
    int wm = wid >> 2, wn = wid & 3;

    f32x4 acc[4][2];
    #pragma unroll
    for (int mi = 0; mi < 4; ++mi)
        #pragma unroll
        for (int ni = 0; ni < 2; ++ni)
            acc[mi][ni] = (f32x4){0.f, 0.f, 0.f, 0.f};

#define STAGE(pg, k0)                                                              \
    do {                                                                           \
        _Pragma("unroll")                                                          \
        for (int s_ = 0; s_ < 4; ++s_) {                                           \
            int g_ = tid + s_ * 512;                                               \
            int gg_ = g_ & 1023;                                                   \
            int row_ = gg_ >> 3, cg_ = gg_ & 7;                                    \
            int csw_ = cg_ ^ (row_ & 7);                                           \
            const ushort* src_;                                                    \
            ushort* dst_;                                                          \
            if (g_ < 1024) {                                                       \
                src_ = A + (size_t)(ar0 + row_) * GK + (k0) + csw_ * 8;            \
                dst_ = &Asm[pg][gg_ * 8];                                          \
            } else {                                                               \
                src_ = Bt + (size_t)(bc0 + row_) * GK + (k0) + csw_ * 8;           \
                dst_ = &Bsm[pg][gg_ * 8];                                          \
            }                                                                      \
            __builtin_amdgcn_global_load_lds(                                      \
                (const __attribute__((address_space(1))) void*)src_,               \
                (__attribute__((address_space(3))) void*)dst_, 16, 0, 0);          \
        }                                                                          \
    } while (0)

    STAGE(0, kbase);
    __syncthreads();
    int pg = 0;
    for (int kt = 0; kt < NKT; ++kt) {
        if (kt + 1 < NKT) STAGE(pg ^ 1, kbase + (kt + 1) * 64);
        const ushort* Ab = Asm[pg];
        const ushort* Bb = Bsm[pg];
        short8 afr[4][2], bfr[2][2];
        #pragma unroll
        for (int mi = 0; mi < 4; ++mi)
            #pragma unroll
            for (int ks = 0; ks < 2; ++ks) {
                int row = wm * 64 + mi * 16 + (lane & 15);
                int gs = (ks * 4 + (lane >> 4)) ^ (row & 7);
                afr[mi][ks] = *(const short8*)&Ab[row * 64 + gs * 8];
            }
        #pragma unroll
        for (int ni = 0; ni < 2; ++ni)
            #pragma unroll
            for (int ks = 0; ks < 2; ++ks) {
                int row = wn * 32 + ni * 16 + (lane & 15);
                int gs = (ks * 4 + (lane >> 4)) ^ (row & 7);
                bfr[ni][ks] = *(const short8*)&Bb[row * 64 + gs * 8];
            }
        #pragma unroll
        for (int ks = 0; ks < 2; ++ks)
            #pragma unroll
            for (int mi = 0; mi < 4; ++mi)
                #pragma unroll
                for (int ni = 0; ni < 2; ++ni)
                    acc[mi][ni] = __builtin_amdgcn_mfma_f32_16x16x32_bf16(
                        afr[mi][ks], bfr[ni][ks], acc[mi][ni], 0, 0, 0);
        __syncthreads();
        pg ^= 1;
    }
#undef STAGE

    float* outp = parts + (size_t)sp * GN * GON;
    #pragma unroll
    for (int mi = 0; mi < 4; ++mi)
        #pragma unroll
        for (int ni = 0; ni < 2; ++ni)
            #pragma unroll
            for (int r = 0; r < 4; ++r) {
                int row = ar0 + wm * 64 + mi * 16 + (lane >> 4) * 4 + r;
                int col = bc0 + wn * 32 + ni * 16 + (lane & 15);
                outp[(size_t)row * GON + col] = acc[mi][ni][r];
            }
}

// ---------------- reduce partials + fpb + LayerNorm -> d_out ----------------
__global__ __launch_bounds__(256) void final_reduce_ln(
    const float* __restrict__ parts, float* __restrict__ out,
    const float* __restrict__ fpb, const float* __restrict__ fng,
    const float* __restrict__ fnb)
{
    int row = blockIdx.x * 4 + (threadIdx.x >> 6);
    int lane = threadIdx.x & 63;
    float v[8];
    float sum = 0.f;
    #pragma unroll
    for (int cc = 0; cc < 8; ++cc) {
        int o = lane + (cc << 6);
        float a = 0.f;
        #pragma unroll
        for (int s = 0; s < SPLITK; ++s)
            a += parts[(size_t)s * GN * GON + (size_t)row * GON + o];
        v[cc] = a + fpb[o];
        sum += v[cc];
    }
    #pragma unroll
    for (int off = 32; off >= 1; off >>= 1) sum += __shfl_xor(sum, off, 64);
    float mu = sum * (1.f / GON);
    float sq = 0.f;
    #pragma unroll
    for (int cc = 0; cc < 8; ++cc) { float d = v[cc] - mu; sq += d * d; }
    #pragma unroll
    for (int off = 32; off >= 1; off >>= 1) sq += __shfl_xor(sq, off, 64);
    float inv = rsqrtf(sq * (1.f / GON) + 1e-5f);
    #pragma unroll
    for (int cc = 0; cc < 8; ++cc) {
        int o = lane + (cc << 6);
        out[(size_t)row * GON + o] = (v[cc] - mu) * inv * fng[o] + fnb[o];
    }
}

extern "C" void kernel_launch(void* const* d_in, const int* in_sizes, int n_in,
                              void* d_out, int out_size, void* d_ws, size_t ws_size,
                              hipStream_t stream) {
    (void)in_sizes; (void)n_in; (void)out_size; (void)ws_size;
    const float* pose = (const float*)d_in[0];
    const float *W0 = (const float*)d_in[1],  *as0 = (const float*)d_in[2],
                *ad0 = (const float*)d_in[3], *bg0 = (const float*)d_in[4],
                *R0 = (const float*)d_in[5],  *g0v = (const float*)d_in[6],
                *b0v = (const float*)d_in[7];
    const float *W1 = (const float*)d_in[8],  *as1 = (const float*)d_in[9],
                *ad1 = (const float*)d_in[10],*bg1 = (const float*)d_in[11],
                *R1 = (const float*)d_in[12], *g1v = (const float*)d_in[13],
                *b1v = (const float*)d_in[14];
    const float *W2 = (const float*)d_in[15], *as2 = (const float*)d_in[16],
                *ad2 = (const float*)d_in[17],*bg2 = (const float*)d_in[18],
                *R2 = (const float*)d_in[19], *g2v = (const float*)d_in[20],
                *b2v = (const float*)d_in[21];
    const float* fpW = (const float*)d_in[22];
    const float* fpb = (const float*)d_in[23];
    const float* fng = (const float*)d_in[24];
    const float* fnb = (const float*)d_in[25];

    // workspace: xg | Bt | parts | wt (86016) | wex (14336)
    ushort* xg = (ushort*)d_ws;                               // 52,428,800 B
    ushort* Bt = xg + (size_t)GN * GK;                        // +13,107,200 B
    float* parts = (float*)(Bt + (size_t)GON * GK);           // +33,554,432 B
    ushort* wsm = (ushort*)(parts + (size_t)SPLITK * GN * GON); // +172,032 B
    ushort *Wt0 = wsm,          *Rt0 = wsm + 2048;
    ushort *Wt1 = wsm + 4096,   *Rt1 = wsm + 12288;
    ushort *Wt2 = wsm + 20480,  *Rt2 = wsm + 53248;
    ushort* wex = wsm + 86016;                                // +28,672 B (~99.29 MB total)
    ushort *wex0 = wex, *wex1 = wex + 2048, *wex2 = wex + 6144;
    float* out = (float*)d_out;

    prep_all<<<392 + (GK / 64) * (GON / 64), 256, 0, stream>>>(
        W0, R0, W1, R1, W2, R2,
        as0, ad0, as1, ad1, as2, ad2,
        fpW, wsm, wex, Bt);
    gat_mfma<<<GN, 256, 0, stream>>>(pose,
        Wt0, Rt0, Wt1, Rt1, Wt2, Rt2,
        wex0, wex1, wex2,
        bg0, g0v, b0v,
        bg1, g1v, b1v,
        bg2, g2v, b2v, xg);
    final_gemm_mfma<<<64 * SPLITK, 512, 0, stream>>>(xg, Bt, parts);
    final_reduce_ln<<<GN / 4, 256, 0, stream>>>(parts, out, fpb, fng, fnb);
}

// Round 13
// 163.286 us; speedup vs baseline: 1.1592x; 1.0554x over previous
//
#include <hip/hip_runtime.h>
#include <hip/hip_bf16.h>
#include <math.h>

#define J 50
#define GN 2048          // B*T graphs
#define GK 12800         // J*256
#define GON 512          // pose dim

#define SPLITK 8
#define BKC (GK / SPLITK)   // 1600 K per split
#define NKT (BKC / 64)      // 25 K-steps of 64

typedef short short8 __attribute__((ext_vector_type(8)));
typedef float f32x4 __attribute__((ext_vector_type(4)));

__device__ __forceinline__ float lrelu(float x) { return x > 0.f ? x : 0.2f * x; }
__device__ __forceinline__ ushort f2bu(float f) { __hip_bfloat16 h = __float2bfloat16(f); return *(ushort*)&h; }

// fast GELU: 0.5y(1+tanh(c(y+0.044715y^3))) = y/(1+exp(-2c*u)); rcp approx for the divide
__device__ __forceinline__ float gelu_fast(float y) {
    float u = y * (1.f + 0.044715f * y * y);
    float t = __expf(-1.5957691216f * u);
    return y * __builtin_amdgcn_rcpf(1.f + t);
}

// VALU-only 16-lane row sum via DPP row_ror (no LDS pipe)
__device__ __forceinline__ float dpp_sum16(float s) {
    int v;
    v = __builtin_amdgcn_update_dpp(0, __builtin_bit_cast(int, s), 0x128, 0xF, 0xF, true);
    s += __builtin_bit_cast(float, v);   // += ror 8
    v = __builtin_amdgcn_update_dpp(0, __builtin_bit_cast(int, s), 0x124, 0xF, 0xF, true);
    s += __builtin_bit_cast(float, v);   // += ror 4
    v = __builtin_amdgcn_update_dpp(0, __builtin_bit_cast(int, s), 0x122, 0xF, 0xF, true);
    s += __builtin_bit_cast(float, v);   // += ror 2
    v = __builtin_amdgcn_update_dpp(0, __builtin_bit_cast(int, s), 0x121, 0xF, 0xF, true);
    s += __builtin_bit_cast(float, v);   // += ror 1
    return s;
}

// ================= fused 3-layer GAT (R12 structure + setprio on MFMA clusters) =================
// 1 graph/block, 256 threads = 4 waves; wave w owns head w.
// Scores folded into MFMA via Wex = [W@as | W@ad | 0...]; alphas wave-local (no barrier).

template<int DIN, int KPAD, int DOUT, bool LAST>
__device__ __forceinline__ void gat_layer_v3(
    int tid, ushort* xbf, float* esW, float* Acoef, float* statsC, float* statsN,
    const ushort* __restrict__ Wt, const ushort* __restrict__ Rt,
    const ushort* __restrict__ Wex,
    const float* __restrict__ bg, const float* __restrict__ gam,
    const float* __restrict__ bet, ushort* __restrict__ gout)
{
    constexpr int NFW = DOUT / 64;              // n-frags per wave (wave cols == head cols)
    constexpr int GRX = KPAD / 8;               // 16B granules per xbf row
    constexpr int XM  = (GRX < 8 ? GRX : 8) - 1;
    constexpr int NKS = KPAD / 32;              // MFMA K-steps
    const int lane = tid & 63, w = tid >> 6;
    const int lr = lane & 15, lg = lane >> 4;

    f32x4 acc[4][NFW];
    f32x4 ext[4];                               // score frag: col0=es, col1=ed

    // ---------- phase A: h = x @ W  +  es/ed = x @ Wex ----------
    #pragma unroll
    for (int m = 0; m < 4; ++m) {
        ext[m] = (f32x4){0.f, 0.f, 0.f, 0.f};
        #pragma unroll
        for (int nf = 0; nf < NFW; ++nf) acc[m][nf] = (f32x4){0.f, 0.f, 0.f, 0.f};
    }
    #pragma unroll
    for (int ks = 0; ks < NKS; ++ks) {
        short8 af[4];
        #pragma unroll
        for (int m = 0; m < 4; ++m) {
            int row = m * 16 + lr;
            int g = (ks * 4 + lg) ^ (row & XM);
            af[m] = *(const short8*)&xbf[(row * GRX + g) * 8];
        }
        __builtin_amdgcn_s_setprio(1);
        #pragma unroll
        for (int nf = 0; nf < NFW; ++nf) {
            int col = (w * NFW + nf) * 16 + lr;
            short8 bf = *(const short8*)&Wt[col * KPAD + ks * 32 + lg * 8];
            #pragma unroll
            for (int m = 0; m < 4; ++m)
                acc[m][nf] = __builtin_amdgcn_mfma_f32_16x16x32_bf16(af[m], bf, acc[m][nf], 0, 0, 0);
        }
        short8 bfe = *(const short8*)&Wex[(w * 16 + lr) * KPAD + ks * 32 + lg * 8];
        #pragma unroll
        for (int m = 0; m < 4; ++m)
            ext[m] = __builtin_amdgcn_mfma_f32_16x16x32_bf16(af[m], bfe, ext[m], 0, 0, 0);
        __builtin_amdgcn_s_setprio(0);
    }

    // ---------- wave-local es/ed spill (no barrier) ----------
    if (lr < 2) {
        float* dstp = &esW[w * 130 + lr * 65];
        #pragma unroll
        for (int m = 0; m < 4; ++m)
            #pragma unroll
            for (int q = 0; q < 4; ++q)
                dstp[m * 16 + lg * 4 + q] = ext[m][q];
    }
    asm volatile("s_waitcnt lgkmcnt(0)" ::: "memory");

    // ---------- wave-local alphas: one lane per row ----------
    {
        int r = lane;
        const float* ew = &esW[w * 130];
        float es0 = ew[r];
        float esm = ew[r > 0 ? r - 1 : 0];
        float esp = ew[r < 63 ? r + 1 : 63];
        float edj = ew[65 + r];
        float e1 = lrelu(es0 + edj);
        float e0 = (r > 0)     ? lrelu(esm + edj) : -1e30f;
        float e2 = (r < J - 1) ? lrelu(esp + edj) : -1e30f;
        float mx = fmaxf(e1, fmaxf(e0, e2));
        float w0 = __expf(e0 - mx), w1 = __expf(e1 - mx), w2 = __expf(e2 - mx);
        float rden = 1.f / (w0 + w1 + w2);
        Acoef[w * 192 + r]       = w0 * rden;
        Acoef[w * 192 + 64 + r]  = w1 * rden;
        Acoef[w * 192 + 128 + r] = w2 * rden;
    }
    asm volatile("s_waitcnt lgkmcnt(0)" ::: "memory");

    // ---------- in-register 3-point stencil: acc <- alpha-weighted agg ----------
    #pragma unroll
    for (int nf = 0; nf < NFW; ++nf) {
        float tmp[4][4];
        #pragma unroll
        for (int m = 0; m < 4; ++m) {
            int rb = m * 16 + lg * 4;
            float4 c0 = *(const float4*)&Acoef[w * 192 + rb];
            float4 c1 = *(const float4*)&Acoef[w * 192 + 64 + rb];
            float4 c2 = *(const float4*)&Acoef[w * 192 + 128 + rb];
            int mp = m > 0 ? m - 1 : 0, mn = m < 3 ? m + 1 : 3;
            float t1 = __shfl(acc[m][nf][3],  (lane + 48) & 63);
            float t2 = __shfl(acc[mp][nf][3], (lane + 48) & 63);
            float hprev = (lg > 0) ? t1 : t2;
            float b1 = __shfl(acc[m][nf][0],  (lane + 16) & 63);
            float b2 = __shfl(acc[mn][nf][0], (lane + 16) & 63);
            float hnext = (lg < 3) ? b1 : b2;
            tmp[m][0] = c0.x * hprev         + c1.x * acc[m][nf][0] + c2.x * acc[m][nf][1];
            tmp[m][1] = c0.y * acc[m][nf][0] + c1.y * acc[m][nf][1] + c2.y * acc[m][nf][2];
            tmp[m][2] = c0.z * acc[m][nf][1] + c1.z * acc[m][nf][2] + c2.z * acc[m][nf][3];
            tmp[m][3] = c0.w * acc[m][nf][2] + c1.w * acc[m][nf][3] + c2.w * hnext;
        }
        #pragma unroll
        for (int m = 0; m < 4; ++m)
            #pragma unroll
            for (int q = 0; q < 4; ++q) acc[m][nf][q] = tmp[m][q];
    }

    // ---------- phase B: acc += x @ R (MFMA accumulates onto agg), then +bias ----------
    #pragma unroll
    for (int ks = 0; ks < NKS; ++ks) {
        short8 af[4];
        #pragma unroll
        for (int m = 0; m < 4; ++m) {
            int row = m * 16 + lr;
            int g = (ks * 4 + lg) ^ (row & XM);
            af[m] = *(const short8*)&xbf[(row * GRX + g) * 8];
        }
        __builtin_amdgcn_s_setprio(1);
        #pragma unroll
        for (int nf = 0; nf < NFW; ++nf) {
            int col = (w * NFW + nf) * 16 + lr;
            short8 bf = *(const short8*)&Rt[col * KPAD + ks * 32 + lg * 8];
            #pragma unroll
            for (int m = 0; m < 4; ++m)
                acc[m][nf] = __builtin_amdgcn_mfma_f32_16x16x32_bf16(af[m], bf, acc[m][nf], 0, 0, 0);
        }
        __builtin_amdgcn_s_setprio(0);
    }
    #pragma unroll
    for (int nf = 0; nf < NFW; ++nf) {
        float bgv = bg[(w * NFW + nf) * 16 + lr];
        #pragma unroll
        for (int m = 0; m < 4; ++m)
            #pragma unroll
            for (int q = 0; q < 4; ++q) acc[m][nf][q] += bgv;
    }

    // ---------- LN stats: DPP row-sum (VALU-only) + LDS atomic ----------
    #pragma unroll
    for (int m = 0; m < 4; ++m)
        #pragma unroll
        for (int q = 0; q < 4; ++q) {
            float s = 0.f, s2 = 0.f;
            #pragma unroll
            for (int nf = 0; nf < NFW; ++nf) {
                float v = acc[m][nf][q];
                s += v; s2 += v * v;
            }
            s  = dpp_sum16(s);
            s2 = dpp_sum16(s2);
            if (lr == 0) {
                int row = m * 16 + lg * 4 + q;
                atomicAdd(&statsC[row * 2], s);
                atomicAdd(&statsC[row * 2 + 1], s2);
            }
        }
    __syncthreads();   // B3
    if (tid < 64) {
        float S = statsC[tid * 2], S2 = statsC[tid * 2 + 1];
        float mu = S * (1.f / DOUT);
        float var = S2 * (1.f / DOUT) - mu * mu;
        statsC[tid * 2] = mu;
        statsC[tid * 2 + 1] = rsqrtf(var + 1e-5f);
    }
    __syncthreads();   // B4

    // ---------- apply LN + GELU (row-outer, 2-fma form) ----------
    constexpr int NGR = DOUT / 8;
    constexpr int NXM = (NGR < 8 ? NGR : 8) - 1;
    {
        float gav[NFW], bev[NFW];
        #pragma unroll
        for (int nf = 0; nf < NFW; ++nf) {
            int col = (w * NFW + nf) * 16 + lr;
            gav[nf] = gam[col]; bev[nf] = bet[col];
        }
        #pragma unroll
        for (int m = 0; m < 4; ++m)
            #pragma unroll
            for (int q = 0; q < 4; ++q) {
                int row = m * 16 + lg * 4 + q;
                float mu = statsC[row * 2], inv = statsC[row * 2 + 1];
                float miv = -mu * inv;
                #pragma unroll
                for (int nf = 0; nf < NFW; ++nf) {
                    int col = (w * NFW + nf) * 16 + lr;
                    float y = fmaf(acc[m][nf][q], inv, miv);
                    y = fmaf(y, gav[nf], bev[nf]);
                    float ge = gelu_fast(y);
                    if (LAST) {
                        if (row < J) gout[row * 256 + col] = f2bu(ge);
                    } else {
                        xbf[(row * NGR + ((col >> 3) ^ (row & NXM))) * 8 + (col & 7)] =
                            (row < J) ? f2bu(ge) : (ushort)0;
                    }
                }
            }
    }
    if (tid < 128) statsN[tid] = 0.f;
    __syncthreads();   // B5
}

__global__ __launch_bounds__(256, 4) void gat_mfma(
    const float* __restrict__ pose,
    const ushort* __restrict__ Wt0, const ushort* __restrict__ Rt0,
    const ushort* __restrict__ Wt1, const ushort* __restrict__ Rt1,
    const ushort* __restrict__ Wt2, const ushort* __restrict__ Rt2,
    const ushort* __restrict__ wex0, const ushort* __restrict__ wex1,
    const ushort* __restrict__ wex2,
    const float* bg0, const float* g0v, const float* b0v,
    const float* bg1, const float* g1v, const float* b1v,
    const float* bg2, const float* g2v, const float* b2v,
    ushort* __restrict__ xg)
{
    __shared__ ushort xbf[64 * 128];   // 16 KB (max KPAD=128)
    __shared__ float esW[4 * 130];     // per-wave es|ed slabs
    __shared__ float Acoef[4 * 192];   // per-wave a0|a1|a2
    __shared__ float sA[128], sB[128]; // double-buffered LN partials
    int g = blockIdx.x, tid = threadIdx.x;

    // load pose -> xbf[64][32] bf16, swizzled (GRX=4, mask 3), zero-padded
    for (int i = tid; i < 64 * 32; i += 256) {
        int row = i >> 5, c = i & 31;
        float v = (row < J && c < 3) ? pose[(size_t)g * (J * 3) + row * 3 + c] : 0.f;
        xbf[(row * 4 + ((c >> 3) ^ (row & 3))) * 8 + (c & 7)] = f2bu(v);
    }
    if (tid < 128) sA[tid] = 0.f;
    __syncthreads();
    gat_layer_v3<3,   32,  64, false>(tid, xbf, esW, Acoef, sA, sB, Wt0, Rt0, wex0,
                                      bg0, g0v, b0v, nullptr);
    gat_layer_v3<64,  64, 128, false>(tid, xbf, esW, Acoef, sB, sA, Wt1, Rt1, wex1,
                                      bg1, g1v, b1v, nullptr);
    gat_layer_v3<128,128, 256, true >(tid, xbf, esW, Acoef, sA, sB, Wt2, Rt2, wex2,
                                      bg2, g2v, b2v, xg + (size_t)g * GK);
}

// ================= fused prep: weights + wex + fpW transpose in one launch =================
// blocks [0,336): transposed bf16 weights; [336,392): Wex fold; [392,1992): fpW -> Bt
__global__ __launch_bounds__(256) void prep_all(
    const float* __restrict__ W0, const float* __restrict__ R0,
    const float* __restrict__ W1, const float* __restrict__ R1,
    const float* __restrict__ W2, const float* __restrict__ R2,
    const float* __restrict__ as0, const float* __restrict__ ad0,
    const float* __restrict__ as1, const float* __restrict__ ad1,
    const float* __restrict__ as2, const float* __restrict__ ad2,
    const float* __restrict__ fpW,
    ushort* __restrict__ wt, ushort* __restrict__ wex, ushort* __restrict__ Bt)
{
    __shared__ float tile[64][65];
    int bid = blockIdx.x, tid = threadIdx.x;
    if (bid < 336) {
        int i = bid * 256 + tid;
        if (i < 2048)       { int n = i >> 5, k = i & 31;                    wt[i] = f2bu(k < 3 ? W0[k * 64 + n] : 0.f); }
        else if (i < 4096)  { int j = i - 2048;  int n = j >> 5, k = j & 31; wt[i] = f2bu(k < 3 ? R0[k * 64 + n] : 0.f); }
        else if (i < 12288) { int j = i - 4096;  int n = j >> 6, k = j & 63; wt[i] = f2bu(W1[k * 128 + n]); }
        else if (i < 20480) { int j = i - 12288; int n = j >> 6, k = j & 63; wt[i] = f2bu(R1[k * 128 + n]); }
        else if (i < 53248) { int j = i - 20480; int n = j >> 7, k = j & 127; wt[i] = f2bu(W2[k * 256 + n]); }
        else if (i < 86016) { int j = i - 53248; int n = j >> 7, k = j & 127; wt[i] = f2bu(R2[k * 256 + n]); }
    } else if (bid < 392) {
        int i = (bid - 336) * 256 + tid;
        const float *as_, *ad_, *W; ushort* dst; int KPAD, DIN, DOUT, idx;
        if (i < 2048)       { idx = i;         KPAD = 32;  DIN = 3;   DOUT = 64;  as_ = as0; ad_ = ad0; W = W0; dst = wex; }
        else if (i < 6144)  { idx = i - 2048;  KPAD = 64;  DIN = 64;  DOUT = 128; as_ = as1; ad_ = ad1; W = W1; dst = wex + 2048; }
        else if (i < 14336) { idx = i - 6144;  KPAD = 128; DIN = 128; DOUT = 256; as_ = as2; ad_ = ad2; W = W2; dst = wex + 6144; }
        else return;
        int k = idx % KPAD;
        int col = (idx / KPAD) & 15;
        int h = idx / (KPAD * 16);
        int C = DOUT / 4;
        float v = 0.f;
        if (col < 2 && k < DIN) {
            const float* a = (col == 0) ? as_ : ad_;
            for (int c = 0; c < C; ++c) v += W[k * DOUT + h * C + c] * a[h * C + c];
        }
        dst[idx] = f2bu(v);
    } else {
        int b = bid - 392;
        int kb = (b >> 3) * 64;
        int nb = (b & 7) * 64;
        #pragma unroll
        for (int i = 0; i < 16; ++i) {
            int idx = tid + i * 256;
            int r = idx >> 6, c = idx & 63;
            tile[r][c] = fpW[(size_t)(kb + r) * GON + nb + c];
        }
        __syncthreads();
        #pragma unroll
        for (int i = 0; i < 16; ++i) {
            int idx = tid + i * 256;
            int nr = idx >> 6, kc = idx & 63;
            Bt[(size_t)(nb + nr) * GK + kb + kc] = f2bu(tile[kc][nr]);
        }
    }
}

// ---------------- MFMA GEMM (unchanged, verified R2-R12) ----------------
__global__ __launch_bounds__(512) void final_gemm_mfma(
    const ushort* __restrict__ A,   // [2048][12800] bf16
    const ushort* __restrict__ Bt,  // [512][12800] bf16
    float* __restrict__ parts)      // [SPLITK][2048][512] f32
{
    __shared__ ushort Asm[2][128 * 64];
    __shared__ ushort Bsm[2][128 * 64];
    int tid = threadIdx.x;
    int bid = blockIdx.x;
    int tileid = bid & 63, sp = bid >> 6;
    int rt = tileid >> 2, ct = tileid & 3;
    int ar0 = rt * 128, bc0 = ct * 128;
    int kbase = sp * BKC;

    int lane = tid & 63, wid = tid >> 6;
    int wm = wid >> 2, wn = wid & 3;

    f32x4 acc[4][2];
    #pragma unroll
    for (int mi = 0; mi < 4; ++mi)
        #pragma unroll
        for (int ni = 0; ni < 2; ++ni)
            acc[mi][ni] = (f32x4){0.f, 0.f, 0.f, 0.f};

#define STAGE(pg, k0)                                                              \
    do {                                                                           \
        _Pragma("unroll")                                                          \
        for (int s_ = 0; s_ < 4; ++s_) {                                           \
            int g_ = tid + s_ * 512;                                               \
            int gg_ = g_ & 1023;                                                   \
            int row_ = gg_ >> 3, cg_ = gg_ & 7;                                    \
            int csw_ = cg_ ^ (row_ & 7);                                           \
            const ushort* src_;                                                    \
            ushort* dst_;                                                          \
            if (g_ < 1024) {                                                       \
                src_ = A + (size_t)(ar0 + row_) * GK + (k0) + csw_ * 8;            \
                dst_ = &Asm[pg][gg_ * 8];                                          \
            } else {                                                               \
                src_ = Bt + (size_t)(bc0 + row_) * GK + (k0) + csw_ * 8;           \
                dst_ = &Bsm[pg][gg_ * 8];                                          \
            }                                                                      \
            __builtin_amdgcn_global_load_lds(                                      \
                (const __attribute__((address_space(1))) void*)src_,               \
                (__attribute__((address_space(3))) void*)dst_, 16, 0, 0);          \
        }                                                                          \
    } while (0)

    STAGE(0, kbase);
    __syncthreads();
    int pg = 0;
    for (int kt = 0; kt < NKT; ++kt) {
        if (kt + 1 < NKT) STAGE(pg ^ 1, kbase + (kt + 1) * 64);
        const ushort* Ab = Asm[pg];
        const ushort* Bb = Bsm[pg];
        short8 afr[4][2], bfr[2][2];
        #pragma unroll
        for (int mi = 0; mi < 4; ++mi)
            #pragma unroll
            for (int ks = 0; ks < 2; ++ks) {
                int row = wm * 64 + mi * 16 + (lane & 15);
                int gs = (ks * 4 + (lane >> 4)) ^ (row & 7);
                afr[mi][ks] = *(const short8*)&Ab[row * 64 + gs * 8];
            }
        #pragma unroll
        for (int ni = 0; ni < 2; ++ni)
            #pragma unroll
            for (int ks = 0; ks < 2; ++ks) {
                int row = wn * 32 + ni * 16 + (lane & 15);
                int gs = (ks * 4 + (lane >> 4)) ^ (row & 7);
                bfr[ni][ks] = *(const short8*)&Bb[row * 64 + gs * 8];
            }
        #pragma unroll
        for (int ks = 0; ks < 2; ++ks)
            #pragma unroll
            for (int mi = 0; mi < 4; ++mi)
                #pragma unroll
                for (int ni = 0; ni < 2; ++ni)
                    acc[mi][ni] = __builtin_amdgcn_mfma_f32_16x16x32_bf16(
                        afr[mi][ks], bfr[ni][ks], acc[mi][ni], 0, 0, 0);
        __syncthreads();
        pg ^= 1;
    }
#undef STAGE

    float* outp = parts + (size_t)sp * GN * GON;
    #pragma unroll
    for (int mi = 0; mi < 4; ++mi)
        #pragma unroll
        for (int ni = 0; ni < 2; ++ni)
            #pragma unroll
            for (int r = 0; r < 4; ++r) {
                int row = ar0 + wm * 64 + mi * 16 + (lane >> 4) * 4 + r;
                int col = bc0 + wn * 32 + ni * 16 + (lane & 15);
                outp[(size_t)row * GON + col] = acc[mi][ni][r];
            }
}

// ---------------- reduce partials + fpb + LayerNorm -> d_out ----------------
__global__ __launch_bounds__(256) void final_reduce_ln(
    const float* __restrict__ parts, float* __restrict__ out,
    const float* __restrict__ fpb, const float* __restrict__ fng,
    const float* __restrict__ fnb)
{
    int row = blockIdx.x * 4 + (threadIdx.x >> 6);
    int lane = threadIdx.x & 63;
    float v[8];
    float sum = 0.f;
    #pragma unroll
    for (int cc = 0; cc < 8; ++cc) {
        int o = lane + (cc << 6);
        float a = 0.f;
        #pragma unroll
        for (int s = 0; s < SPLITK; ++s)
            a += parts[(size_t)s * GN * GON + (size_t)row * GON + o];
        v[cc] = a + fpb[o];
        sum += v[cc];
    }
    #pragma unroll
    for (int off = 32; off >= 1; off >>= 1) sum += __shfl_xor(sum, off, 64);
    float mu = sum * (1.f / GON);
    float sq = 0.f;
    #pragma unroll
    for (int cc = 0; cc < 8; ++cc) { float d = v[cc] - mu; sq += d * d; }
    #pragma unroll
    for (int off = 32; off >= 1; off >>= 1) sq += __shfl_xor(sq, off, 64);
    float inv = rsqrtf(sq * (1.f / GON) + 1e-5f);
    #pragma unroll
    for (int cc = 0; cc < 8; ++cc) {
        int o = lane + (cc << 6);
        out[(size_t)row * GON + o] = (v[cc] - mu) * inv * fng[o] + fnb[o];
    }
}

extern "C" void kernel_launch(void* const* d_in, const int* in_sizes, int n_in,
                              void* d_out, int out_size, void* d_ws, size_t ws_size,
                              hipStream_t stream) {
    (void)in_sizes; (void)n_in; (void)out_size; (void)ws_size;
    const float* pose = (const float*)d_in[0];
    const float *W0 = (const float*)d_in[1],  *as0 = (const float*)d_in[2],
                *ad0 = (const float*)d_in[3], *bg0 = (const float*)d_in[4],
                *R0 = (const float*)d_in[5],  *g0v = (const float*)d_in[6],
                *b0v = (const float*)d_in[7];
    const float *W1 = (const float*)d_in[8],  *as1 = (const float*)d_in[9],
                *ad1 = (const float*)d_in[10],*bg1 = (const float*)d_in[11],
                *R1 = (const float*)d_in[12], *g1v = (const float*)d_in[13],
                *b1v = (const float*)d_in[14];
    const float *W2 = (const float*)d_in[15], *as2 = (const float*)d_in[16],
                *ad2 = (const float*)d_in[17],*bg2 = (const float*)d_in[18],
                *R2 = (const float*)d_in[19], *g2v = (const float*)d_in[20],
                *b2v = (const float*)d_in[21];
    const float* fpW = (const float*)d_in[22];
    const float* fpb = (const float*)d_in[23];
    const float* fng = (const float*)d_in[24];
    const float* fnb = (const float*)d_in[25];

    // workspace: xg | Bt | parts | wt (86016) | wex (14336)
    ushort* xg = (ushort*)d_ws;                               // 52,428,800 B
    ushort* Bt = xg + (size_t)GN * GK;                        // +13,107,200 B
    float* parts = (float*)(Bt + (size_t)GON * GK);           // +33,554,432 B
    ushort* wsm = (ushort*)(parts + (size_t)SPLITK * GN * GON); // +172,032 B
    ushort *Wt0 = wsm,          *Rt0 = wsm + 2048;
    ushort *Wt1 = wsm + 4096,   *Rt1 = wsm + 12288;
    ushort *Wt2 = wsm + 20480,  *Rt2 = wsm + 53248;
    ushort* wex = wsm + 86016;                                // +28,672 B (~99.29 MB total)
    ushort *wex0 = wex, *wex1 = wex + 2048, *wex2 = wex + 6144;
    float* out = (float*)d_out;

    prep_all<<<392 + (GK / 64) * (GON / 64), 256, 0, stream>>>(
        W0, R0, W1, R1, W2, R2,
        as0, ad0, as1, ad1, as2, ad2,
        fpW, wsm, wex, Bt);
    gat_mfma<<<GN, 256, 0, stream>>>(pose,
        Wt0, Rt0, Wt1, Rt1, Wt2, Rt2,
        wex0, wex1, wex2,
        bg0, g0v, b0v,
        bg1, g1v, b1v,
        bg2, g2v, b2v, xg);
    final_gemm_mfma<<<64 * SPLITK, 512, 0, stream>>>(xg, Bt, parts);
    final_reduce_ln<<<GN / 4, 256, 0, stream>>>(parts, out, fpb, fng, fnb);
}

// Round 14
// 157.717 us; speedup vs baseline: 1.2001x; 1.0353x over previous
//
#include <hip/hip_runtime.h>
#include <hip/hip_bf16.h>
#include <math.h>

#define J 50
#define GN 2048          // B*T graphs
#define GK 12800         // J*256
#define GON 512          // pose dim

#define SPLITK 8
#define BKC (GK / SPLITK)   // 1600 K per split
#define NKT (BKC / 64)      // 25 K-steps of 64

typedef short short8 __attribute__((ext_vector_type(8)));
typedef float f32x4 __attribute__((ext_vector_type(4)));

__device__ __forceinline__ float lrelu(float x) { return x > 0.f ? x : 0.2f * x; }
__device__ __forceinline__ ushort f2bu(float f) { __hip_bfloat16 h = __float2bfloat16(f); return *(ushort*)&h; }

// fast GELU: 0.5y(1+tanh(c(y+0.044715y^3))) = y/(1+exp(-2c*u)); rcp approx for the divide
__device__ __forceinline__ float gelu_fast(float y) {
    float u = y * (1.f + 0.044715f * y * y);
    float t = __expf(-1.5957691216f * u);
    return y * __builtin_amdgcn_rcpf(1.f + t);
}

// VALU-only 16-lane row sum via DPP row_ror (no LDS pipe)
__device__ __forceinline__ float dpp_sum16(float s) {
    int v;
    v = __builtin_amdgcn_update_dpp(0, __builtin_bit_cast(int, s), 0x128, 0xF, 0xF, true);
    s += __builtin_bit_cast(float, v);   // += ror 8
    v = __builtin_amdgcn_update_dpp(0, __builtin_bit_cast(int, s), 0x124, 0xF, 0xF, true);
    s += __builtin_bit_cast(float, v);   // += ror 4
    v = __builtin_amdgcn_update_dpp(0, __builtin_bit_cast(int, s), 0x122, 0xF, 0xF, true);
    s += __builtin_bit_cast(float, v);   // += ror 2
    v = __builtin_amdgcn_update_dpp(0, __builtin_bit_cast(int, s), 0x121, 0xF, 0xF, true);
    s += __builtin_bit_cast(float, v);   // += ror 1
    return s;
}

// ================= fused 3-layer GAT (R13 + B4 removal + hoisted stencil shuffles) ==========
// 1 graph/block, 256 threads = 4 waves; wave w owns head w.
// Scores folded into MFMA via Wex = [W@as | W@ad | 0...]; alphas wave-local (no barrier).
// Barriers per layer: B3 (LN atomics visible), B5 (xbf handoff).

template<int DIN, int KPAD, int DOUT, bool LAST>
__device__ __forceinline__ void gat_layer_v3(
    int tid, ushort* xbf, float* esW, float* Acoef, float* statsC, float* statsN,
    const ushort* __restrict__ Wt, const ushort* __restrict__ Rt,
    const ushort* __restrict__ Wex,
    const float* __restrict__ bg, const float* __restrict__ gam,
    const float* __restrict__ bet, ushort* __restrict__ gout)
{
    constexpr int NFW = DOUT / 64;              // n-frags per wave (wave cols == head cols)
    constexpr int GRX = KPAD / 8;               // 16B granules per xbf row
    constexpr int XM  = (GRX < 8 ? GRX : 8) - 1;
    constexpr int NKS = KPAD / 32;              // MFMA K-steps
    const int lane = tid & 63, w = tid >> 6;
    const int lr = lane & 15, lg = lane >> 4;

    f32x4 acc[4][NFW];
    f32x4 ext[4];                               // score frag: col0=es, col1=ed

    // ---------- phase A: h = x @ W  +  es/ed = x @ Wex ----------
    #pragma unroll
    for (int m = 0; m < 4; ++m) {
        ext[m] = (f32x4){0.f, 0.f, 0.f, 0.f};
        #pragma unroll
        for (int nf = 0; nf < NFW; ++nf) acc[m][nf] = (f32x4){0.f, 0.f, 0.f, 0.f};
    }
    #pragma unroll
    for (int ks = 0; ks < NKS; ++ks) {
        short8 af[4];
        #pragma unroll
        for (int m = 0; m < 4; ++m) {
            int row = m * 16 + lr;
            int g = (ks * 4 + lg) ^ (row & XM);
            af[m] = *(const short8*)&xbf[(row * GRX + g) * 8];
        }
        __builtin_amdgcn_s_setprio(1);
        #pragma unroll
        for (int nf = 0; nf < NFW; ++nf) {
            int col = (w * NFW + nf) * 16 + lr;
            short8 bf = *(const short8*)&Wt[col * KPAD + ks * 32 + lg * 8];
            #pragma unroll
            for (int m = 0; m < 4; ++m)
                acc[m][nf] = __builtin_amdgcn_mfma_f32_16x16x32_bf16(af[m], bf, acc[m][nf], 0, 0, 0);
        }
        short8 bfe = *(const short8*)&Wex[(w * 16 + lr) * KPAD + ks * 32 + lg * 8];
        #pragma unroll
        for (int m = 0; m < 4; ++m)
            ext[m] = __builtin_amdgcn_mfma_f32_16x16x32_bf16(af[m], bfe, ext[m], 0, 0, 0);
        __builtin_amdgcn_s_setprio(0);
    }

    // ---------- wave-local es/ed spill (no barrier) ----------
    if (lr < 2) {
        float* dstp = &esW[w * 130 + lr * 65];
        #pragma unroll
        for (int m = 0; m < 4; ++m)
            #pragma unroll
            for (int q = 0; q < 4; ++q)
                dstp[m * 16 + lg * 4 + q] = ext[m][q];
    }
    asm volatile("s_waitcnt lgkmcnt(0)" ::: "memory");

    // ---------- wave-local alphas: one lane per row ----------
    {
        int r = lane;
        const float* ew = &esW[w * 130];
        float es0 = ew[r];
        float esm = ew[r > 0 ? r - 1 : 0];
        float esp = ew[r < 63 ? r + 1 : 63];
        float edj = ew[65 + r];
        float e1 = lrelu(es0 + edj);
        float e0 = (r > 0)     ? lrelu(esm + edj) : -1e30f;
        float e2 = (r < J - 1) ? lrelu(esp + edj) : -1e30f;
        float mx = fmaxf(e1, fmaxf(e0, e2));
        float w0 = __expf(e0 - mx), w1 = __expf(e1 - mx), w2 = __expf(e2 - mx);
        float rden = 1.f / (w0 + w1 + w2);
        Acoef[w * 192 + r]       = w0 * rden;
        Acoef[w * 192 + 64 + r]  = w1 * rden;
        Acoef[w * 192 + 128 + r] = w2 * rden;
    }
    asm volatile("s_waitcnt lgkmcnt(0)" ::: "memory");

    // ---------- in-register 3-point stencil (hoisted rotations: 8 shfl/nf, not 16) ----------
    #pragma unroll
    for (int nf = 0; nf < NFW; ++nf) {
        float rp[4], rn[4];
        #pragma unroll
        for (int m = 0; m < 4; ++m) {
            rp[m] = __shfl(acc[m][nf][3], (lane + 48) & 63);  // from lane-16 group
            rn[m] = __shfl(acc[m][nf][0], (lane + 16) & 63);  // from lane+16 group
        }
        float tmp[4][4];
        #pragma unroll
        for (int m = 0; m < 4; ++m) {
            int rb = m * 16 + lg * 4;
            float4 c0 = *(const float4*)&Acoef[w * 192 + rb];
            float4 c1 = *(const float4*)&Acoef[w * 192 + 64 + rb];
            float4 c2 = *(const float4*)&Acoef[w * 192 + 128 + rb];
            int mp = m > 0 ? m - 1 : 0, mn = m < 3 ? m + 1 : 3;
            float hprev = (lg > 0) ? rp[m] : rp[mp];
            float hnext = (lg < 3) ? rn[m] : rn[mn];
            tmp[m][0] = c0.x * hprev         + c1.x * acc[m][nf][0] + c2.x * acc[m][nf][1];
            tmp[m][1] = c0.y * acc[m][nf][0] + c1.y * acc[m][nf][1] + c2.y * acc[m][nf][2];
            tmp[m][2] = c0.z * acc[m][nf][1] + c1.z * acc[m][nf][2] + c2.z * acc[m][nf][3];
            tmp[m][3] = c0.w * acc[m][nf][2] + c1.w * acc[m][nf][3] + c2.w * hnext;
        }
        #pragma unroll
        for (int m = 0; m < 4; ++m)
            #pragma unroll
            for (int q = 0; q < 4; ++q) acc[m][nf][q] = tmp[m][q];
    }

    // ---------- phase B: acc += x @ R (MFMA accumulates onto agg), then +bias ----------
    #pragma unroll
    for (int ks = 0; ks < NKS; ++ks) {
        short8 af[4];
        #pragma unroll
        for (int m = 0; m < 4; ++m) {
            int row = m * 16 + lr;
            int g = (ks * 4 + lg) ^ (row & XM);
            af[m] = *(const short8*)&xbf[(row * GRX + g) * 8];
        }
        __builtin_amdgcn_s_setprio(1);
        #pragma unroll
        for (int nf = 0; nf < NFW; ++nf) {
            int col = (w * NFW + nf) * 16 + lr;
            short8 bf = *(const short8*)&Rt[col * KPAD + ks * 32 + lg * 8];
            #pragma unroll
            for (int m = 0; m < 4; ++m)
                acc[m][nf] = __builtin_amdgcn_mfma_f32_16x16x32_bf16(af[m], bf, acc[m][nf], 0, 0, 0);
        }
        __builtin_amdgcn_s_setprio(0);
    }
    #pragma unroll
    for (int nf = 0; nf < NFW; ++nf) {
        float bgv = bg[(w * NFW + nf) * 16 + lr];
        #pragma unroll
        for (int m = 0; m < 4; ++m)
            #pragma unroll
            for (int q = 0; q < 4; ++q) acc[m][nf][q] += bgv;
    }

    // ---------- LN stats: DPP row-sum (VALU-only) + LDS atomic ----------
    #pragma unroll
    for (int m = 0; m < 4; ++m)
        #pragma unroll
        for (int q = 0; q < 4; ++q) {
            float s = 0.f, s2 = 0.f;
            #pragma unroll
            for (int nf = 0; nf < NFW; ++nf) {
                float v = acc[m][nf][q];
                s += v; s2 += v * v;
            }
            s  = dpp_sum16(s);
            s2 = dpp_sum16(s2);
            if (lr == 0) {
                int row = m * 16 + lg * 4 + q;
                atomicAdd(&statsC[row * 2], s);
                atomicAdd(&statsC[row * 2 + 1], s2);
            }
        }
    __syncthreads();   // B3 (atomics visible; no finalize barrier — per-thread fold below)

    // ---------- apply LN + GELU (per-thread mu/inv from raw sums; row-outer, 2-fma) ----------
    constexpr int NGR = DOUT / 8;
    constexpr int NXM = (NGR < 8 ? NGR : 8) - 1;
    {
        float gav[NFW], bev[NFW];
        #pragma unroll
        for (int nf = 0; nf < NFW; ++nf) {
            int col = (w * NFW + nf) * 16 + lr;
            gav[nf] = gam[col]; bev[nf] = bet[col];
        }
        #pragma unroll
        for (int m = 0; m < 4; ++m)
            #pragma unroll
            for (int q = 0; q < 4; ++q) {
                int row = m * 16 + lg * 4 + q;
                float S = statsC[row * 2], S2 = statsC[row * 2 + 1];
                float mu = S * (1.f / DOUT);
                float inv = rsqrtf(fmaf(S2, 1.f / DOUT, -mu * mu) + 1e-5f);
                float miv = -mu * inv;
                #pragma unroll
                for (int nf = 0; nf < NFW; ++nf) {
                    int col = (w * NFW + nf) * 16 + lr;
                    float y = fmaf(acc[m][nf][q], inv, miv);
                    y = fmaf(y, gav[nf], bev[nf]);
                    float ge = gelu_fast(y);
                    if (LAST) {
                        if (row < J) gout[row * 256 + col] = f2bu(ge);
                    } else {
                        xbf[(row * NGR + ((col >> 3) ^ (row & NXM))) * 8 + (col & 7)] =
                            (row < J) ? f2bu(ge) : (ushort)0;
                    }
                }
            }
    }
    if (tid < 128) statsN[tid] = 0.f;
    __syncthreads();   // B5
}

__global__ __launch_bounds__(256, 4) void gat_mfma(
    const float* __restrict__ pose,
    const ushort* __restrict__ Wt0, const ushort* __restrict__ Rt0,
    const ushort* __restrict__ Wt1, const ushort* __restrict__ Rt1,
    const ushort* __restrict__ Wt2, const ushort* __restrict__ Rt2,
    const ushort* __restrict__ wex0, const ushort* __restrict__ wex1,
    const ushort* __restrict__ wex2,
    const float* bg0, const float* g0v, const float* b0v,
    const float* bg1, const float* g1v, const float* b1v,
    const float* bg2, const float* g2v, const float* b2v,
    ushort* __restrict__ xg)
{
    __shared__ ushort xbf[64 * 128];   // 16 KB (max KPAD=128)
    __shared__ float esW[4 * 130];     // per-wave es|ed slabs
    __shared__ float Acoef[4 * 192];   // per-wave a0|a1|a2
    __shared__ float sA[128], sB[128]; // double-buffered LN partials
    int g = blockIdx.x, tid = threadIdx.x;

    // load pose -> xbf[64][32] bf16, swizzled (GRX=4, mask 3), zero-padded
    for (int i = tid; i < 64 * 32; i += 256) {
        int row = i >> 5, c = i & 31;
        float v = (row < J && c < 3) ? pose[(size_t)g * (J * 3) + row * 3 + c] : 0.f;
        xbf[(row * 4 + ((c >> 3) ^ (row & 3))) * 8 + (c & 7)] = f2bu(v);
    }
    if (tid < 128) sA[tid] = 0.f;
    __syncthreads();
    gat_layer_v3<3,   32,  64, false>(tid, xbf, esW, Acoef, sA, sB, Wt0, Rt0, wex0,
                                      bg0, g0v, b0v, nullptr);
    gat_layer_v3<64,  64, 128, false>(tid, xbf, esW, Acoef, sB, sA, Wt1, Rt1, wex1,
                                      bg1, g1v, b1v, nullptr);
    gat_layer_v3<128,128, 256, true >(tid, xbf, esW, Acoef, sA, sB, Wt2, Rt2, wex2,
                                      bg2, g2v, b2v, xg + (size_t)g * GK);
}

// ================= fused prep: weights + wex + fpW transpose in one launch =================
// blocks [0,336): transposed bf16 weights; [336,392): Wex fold; [392,1992): fpW -> Bt
__global__ __launch_bounds__(256) void prep_all(
    const float* __restrict__ W0, const float* __restrict__ R0,
    const float* __restrict__ W1, const float* __restrict__ R1,
    const float* __restrict__ W2, const float* __restrict__ R2,
    const float* __restrict__ as0, const float* __restrict__ ad0,
    const float* __restrict__ as1, const float* __restrict__ ad1,
    const float* __restrict__ as2, const float* __restrict__ ad2,
    const float* __restrict__ fpW,
    ushort* __restrict__ wt, ushort* __restrict__ wex, ushort* __restrict__ Bt)
{
    __shared__ float tile[64][65];
    int bid = blockIdx.x, tid = threadIdx.x;
    if (bid < 336) {
        int i = bid * 256 + tid;
        if (i < 2048)       { int n = i >> 5, k = i & 31;                    wt[i] = f2bu(k < 3 ? W0[k * 64 + n] : 0.f); }
        else if (i < 4096)  { int j = i - 2048;  int n = j >> 5, k = j & 31; wt[i] = f2bu(k < 3 ? R0[k * 64 + n] : 0.f); }
        else if (i < 12288) { int j = i - 4096;  int n = j >> 6, k = j & 63; wt[i] = f2bu(W1[k * 128 + n]); }
        else if (i < 20480) { int j = i - 12288; int n = j >> 6, k = j & 63; wt[i] = f2bu(R1[k * 128 + n]); }
        else if (i < 53248) { int j = i - 20480; int n = j >> 7, k = j & 127; wt[i] = f2bu(W2[k * 256 + n]); }
        else if (i < 86016) { int j = i - 53248; int n = j >> 7, k = j & 127; wt[i] = f2bu(R2[k * 256 + n]); }
    } else if (bid < 392) {
        int i = (bid - 336) * 256 + tid;
        const float *as_, *ad_, *W; ushort* dst; int KPAD, DIN, DOUT, idx;
        if (i < 2048)       { idx = i;         KPAD = 32;  DIN = 3;   DOUT = 64;  as_ = as0; ad_ = ad0; W = W0; dst = wex; }
        else if (i < 6144)  { idx = i - 2048;  KPAD = 64;  DIN = 64;  DOUT = 128; as_ = as1; ad_ = ad1; W = W1; dst = wex + 2048; }
        else if (i < 14336) { idx = i - 6144;  KPAD = 128; DIN = 128; DOUT = 256; as_ = as2; ad_ = ad2; W = W2; dst = wex + 6144; }
        else return;
        int k = idx % KPAD;
        int col = (idx / KPAD) & 15;
        int h = idx / (KPAD * 16);
        int C = DOUT / 4;
        float v = 0.f;
        if (col < 2 && k < DIN) {
            const float* a = (col == 0) ? as_ : ad_;
            for (int c = 0; c < C; ++c) v += W[k * DOUT + h * C + c] * a[h * C + c];
        }
        dst[idx] = f2bu(v);
    } else {
        int b = bid - 392;
        int kb = (b >> 3) * 64;
        int nb = (b & 7) * 64;
        #pragma unroll
        for (int i = 0; i < 16; ++i) {
            int idx = tid + i * 256;
            int r = idx >> 6, c = idx & 63;
            tile[r][c] = fpW[(size_t)(kb + r) * GON + nb + c];
        }
        __syncthreads();
        #pragma unroll
        for (int i = 0; i < 16; ++i) {
            int idx = tid + i * 256;
            int nr = idx >> 6, kc = idx & 63;
            Bt[(size_t)(nb + nr) * GK + kb + kc] = f2bu(tile[kc][nr]);
        }
    }
}

// ---------------- MFMA GEMM (unchanged, verified R2-R13) ----------------
__global__ __launch_bounds__(512) void final_gemm_mfma(
    const ushort* __restrict__ A,   // [2048][12800] bf16
    const ushort* __restrict__ Bt,  // [512][12800] bf16
    float* __restrict__ parts)      // [SPLITK][2048][512] f32
{
    __shared__ ushort Asm[2][128 * 64];
    __shared__ ushort Bsm[2][128 * 64];
    int tid = threadIdx.x;
    int bid = blockIdx.x;
    int tileid = bid & 63, sp = bid >> 6;
    int rt = tileid >> 2, ct = tileid & 3;
    int ar0 = rt * 128, bc0 = ct * 128;
    int kbase = sp * BKC;

    int lane = tid & 63, wid = tid >> 6;
    int wm = wid >> 2, wn = wid & 3;

    f32x4 acc[4][2];
    #pragma unroll
    for (int mi = 0; mi < 4; ++mi)
        #pragma unroll
        for (int ni = 0; ni < 2; ++ni)
            acc[mi][ni] = (f32x4){0.f, 0.f, 0.f, 0.f};

#define STAGE(pg, k0)                                                              \
    do {                                                                           \
        _Pragma("unroll")                                                          \
        for (int s_ = 0; s_ < 4; ++s_) {                                           \
            int g_ = tid + s_ * 512;                                               \
            int gg_ = g_ & 1023;                                                   \
            int row_ = gg_ >> 3, cg_ = gg_ & 7;                                    \
            int csw_ = cg_ ^ (row_ & 7);                                           \
            const ushort* src_;                                                    \
            ushort* dst_;                                                          \
            if (g_ < 1024) {                                                       \
                src_ = A + (size_t)(ar0 + row_) * GK + (k0) + csw_ * 8;            \
                dst_ = &Asm[pg][gg_ * 8];                                          \
            } else {                                                               \
                src_ = Bt + (size_t)(bc0 + row_) * GK + (k0) + csw_ * 8;           \
                dst_ = &Bsm[pg][gg_ * 8];                                          \
            }                                                                      \
            __builtin_amdgcn_global_load_lds(                                      \
                (const __attribute__((address_space(1))) void*)src_,               \
                (__attribute__((address_space(3))) void*)dst_, 16, 0, 0);          \
        }                                                                          \
    } while (0)

    STAGE(0, kbase);
    __syncthreads();
    int pg = 0;
    for (int kt = 0; kt < NKT; ++kt) {
        if (kt + 1 < NKT) STAGE(pg ^ 1, kbase + (kt + 1) * 64);
        const ushort* Ab = Asm[pg];
        const ushort* Bb = Bsm[pg];
        short8 afr[4][2], bfr[2][2];
        #pragma unroll
        for (int mi = 0; mi < 4; ++mi)
            #pragma unroll
            for (int ks = 0; ks < 2; ++ks) {
                int row = wm * 64 + mi * 16 + (lane & 15);
                int gs = (ks * 4 + (lane >> 4)) ^ (row & 7);
                afr[mi][ks] = *(const short8*)&Ab[row * 64 + gs * 8];
            }
        #pragma unroll
        for (int ni = 0; ni < 2; ++ni)
            #pragma unroll
            for (int ks = 0; ks < 2; ++ks) {
                int row = wn * 32 + ni * 16 + (lane & 15);
                int gs = (ks * 4 + (lane >> 4)) ^ (row & 7);
                bfr[ni][ks] = *(const short8*)&Bb[row * 64 + gs * 8];
            }
        #pragma unroll
        for (int ks = 0; ks < 2; ++ks)
            #pragma unroll
            for (int mi = 0; mi < 4; ++mi)
                #pragma unroll
                for (int ni = 0; ni < 2; ++ni)
                    acc[mi][ni] = __builtin_amdgcn_mfma_f32_16x16x32_bf16(
                        afr[mi][ks], bfr[ni][ks], acc[mi][ni], 0, 0, 0);
        __syncthreads();
        pg ^= 1;
    }
#undef STAGE

    float* outp = parts + (size_t)sp * GN * GON;
    #pragma unroll
    for (int mi = 0; mi < 4; ++mi)
        #pragma unroll
        for (int ni = 0; ni < 2; ++ni)
            #pragma unroll
            for (int r = 0; r < 4; ++r) {
                int row = ar0 + wm * 64 + mi * 16 + (lane >> 4) * 4 + r;
                int col = bc0 + wn * 32 + ni * 16 + (lane & 15);
                outp[(size_t)row * GON + col] = acc[mi][ni][r];
            }
}

// ---------------- reduce partials + fpb + LayerNorm -> d_out ----------------
__global__ __launch_bounds__(256) void final_reduce_ln(
    const float* __restrict__ parts, float* __restrict__ out,
    const float* __restrict__ fpb, const float* __restrict__ fng,
    const float* __restrict__ fnb)
{
    int row = blockIdx.x * 4 + (threadIdx.x >> 6);
    int lane = threadIdx.x & 63;
    float v[8];
    float sum = 0.f;
    #pragma unroll
    for (int cc = 0; cc < 8; ++cc) {
        int o = lane + (cc << 6);
        float a = 0.f;
        #pragma unroll
        for (int s = 0; s < SPLITK; ++s)
            a += parts[(size_t)s * GN * GON + (size_t)row * GON + o];
        v[cc] = a + fpb[o];
        sum += v[cc];
    }
    #pragma unroll
    for (int off = 32; off >= 1; off >>= 1) sum += __shfl_xor(sum, off, 64);
    float mu = sum * (1.f / GON);
    float sq = 0.f;
    #pragma unroll
    for (int cc = 0; cc < 8; ++cc) { float d = v[cc] - mu; sq += d * d; }
    #pragma unroll
    for (int off = 32; off >= 1; off >>= 1) sq += __shfl_xor(sq, off, 64);
    float inv = rsqrtf(sq * (1.f / GON) + 1e-5f);
    #pragma unroll
    for (int cc = 0; cc < 8; ++cc) {
        int o = lane + (cc << 6);
        out[(size_t)row * GON + o] = (v[cc] - mu) * inv * fng[o] + fnb[o];
    }
}

extern "C" void kernel_launch(void* const* d_in, const int* in_sizes, int n_in,
                              void* d_out, int out_size, void* d_ws, size_t ws_size,
                              hipStream_t stream) {
    (void)in_sizes; (void)n_in; (void)out_size; (void)ws_size;
    const float* pose = (const float*)d_in[0];
    const float *W0 = (const float*)d_in[1],  *as0 = (const float*)d_in[2],
                *ad0 = (const float*)d_in[3], *bg0 = (const float*)d_in[4],
                *R0 = (const float*)d_in[5],  *g0v = (const float*)d_in[6],
                *b0v = (const float*)d_in[7];
    const float *W1 = (const float*)d_in[8],  *as1 = (const float*)d_in[9],
                *ad1 = (const float*)d_in[10],*bg1 = (const float*)d_in[11],
                *R1 = (const float*)d_in[12], *g1v = (const float*)d_in[13],
                *b1v = (const float*)d_in[14];
    const float *W2 = (const float*)d_in[15], *as2 = (const float*)d_in[16],
                *ad2 = (const float*)d_in[17],*bg2 = (const float*)d_in[18],
                *R2 = (const float*)d_in[19], *g2v = (const float*)d_in[20],
                *b2v = (const float*)d_in[21];
    const float* fpW = (const float*)d_in[22];
    const float* fpb = (const float*)d_in[23];
    const float* fng = (const float*)d_in[24];
    const float* fnb = (const float*)d_in[25];

    // workspace: xg | Bt | parts | wt (86016) | wex (14336)
    ushort* xg = (ushort*)d_ws;                               // 52,428,800 B
    ushort* Bt = xg + (size_t)GN * GK;                        // +13,107,200 B
    float* parts = (float*)(Bt + (size_t)GON * GK);           // +33,554,432 B
    ushort* wsm = (ushort*)(parts + (size_t)SPLITK * GN * GON); // +172,032 B
    ushort *Wt0 = wsm,          *Rt0 = wsm + 2048;
    ushort *Wt1 = wsm + 4096,   *Rt1 = wsm + 12288;
    ushort *Wt2 = wsm + 20480,  *Rt2 = wsm + 53248;
    ushort* wex = wsm + 86016;                                // +28,672 B (~99.29 MB total)
    ushort *wex0 = wex, *wex1 = wex + 2048, *wex2 = wex + 6144;
    float* out = (float*)d_out;

    prep_all<<<392 + (GK / 64) * (GON / 64), 256, 0, stream>>>(
        W0, R0, W1, R1, W2, R2,
        as0, ad0, as1, ad1, as2, ad2,
        fpW, wsm, wex, Bt);
    gat_mfma<<<GN, 256, 0, stream>>>(pose,
        Wt0, Rt0, Wt1, Rt1, Wt2, Rt2,
        wex0, wex1, wex2,
        bg0, g0v, b0v,
        bg1, g1v, b1v,
        bg2, g2v, b2v, xg);
    final_gemm_mfma<<<64 * SPLITK, 512, 0, stream>>>(xg, Bt, parts);
    final_reduce_ln<<<GN / 4, 256, 0, stream>>>(parts, out, fpb, fng, fnb);
}